// Round 1
// baseline (459.080 us; speedup 1.0000x reference)
//
#include <hip/hip_runtime.h>
#include <cstdint>
#include <cstddef>

#define T_TOK 1024
#define H_DIM 1024
#define I_DIM 2816
#define E_NUM 8
#define PAIRS 2048  // T_TOK * top_k(=2)

typedef __attribute__((ext_vector_type(4))) float f32x4;
typedef __attribute__((ext_vector_type(8))) short short8v;
typedef __attribute__((ext_vector_type(4))) unsigned int u32x4;

// ---------- fp8 e4m3fn emulation (saturating clip + RNE round-trip) ----------
__device__ __forceinline__ unsigned short bfbits(float q) {
  // fp8 values have <=4 significant bits -> truncation to bf16 is exact
  return (unsigned short)(__float_as_uint(q) >> 16);
}

__device__ __forceinline__ float fp8_round_sw(float v) {
  // v already clipped to [-448, 448]
  unsigned bits = __float_as_uint(v);
  unsigned sgn = bits & 0x80000000u;
  float a = __uint_as_float(bits & 0x7fffffffu);
  float q;
  if (a < 0.015625f) {                 // subnormal range, step 2^-9
    q = rintf(a * 512.f) * (1.f / 512.f);
  } else {
    unsigned b = __float_as_uint(a);
    unsigned rnd = 0x7FFFFu + ((b >> 20) & 1u);  // RNE on 20 dropped bits
    b = (b + rnd) & 0xFFF00000u;
    q = __uint_as_float(b);
  }
  return __uint_as_float(__float_as_uint(q) | sgn);
}

__device__ __forceinline__ void fp8_pair(float a, float b, float& qa, float& qb) {
  a = fminf(448.f, fmaxf(-448.f, a));
  b = fminf(448.f, fmaxf(-448.f, b));
#if __has_builtin(__builtin_amdgcn_cvt_pk_fp8_f32) && __has_builtin(__builtin_amdgcn_cvt_f32_fp8)
  unsigned p = (unsigned)__builtin_amdgcn_cvt_pk_fp8_f32(a, b, 0, false);
  qa = __builtin_amdgcn_cvt_f32_fp8(p, 0);
  qb = __builtin_amdgcn_cvt_f32_fp8(p, 1);
#else
  qa = fp8_round_sw(a);
  qb = fp8_round_sw(b);
#endif
}

__device__ __forceinline__ float fp8_one(float v) {
  float qa, qb;
  fp8_pair(v, v, qa, qb);
  return qa;
}

// ---------- routing: softmax -> top2 -> renorm (== softmax over top-2 logits) ----------
__global__ __launch_bounds__(256) void routing_k(const float* __restrict__ logits,
                                                 int* __restrict__ tk_id,
                                                 float* __restrict__ tk_w,
                                                 int* __restrict__ cnt) {
  int t = blockIdx.x * 256 + threadIdx.x;
  if (t >= T_TOK) return;
  float l[E_NUM];
#pragma unroll
  for (int j = 0; j < E_NUM; j++) l[j] = logits[t * E_NUM + j];
  int i0 = 0; float b0 = l[0];
#pragma unroll
  for (int j = 1; j < E_NUM; j++) { if (l[j] > b0) { b0 = l[j]; i0 = j; } }
  int i1 = -1; float b1 = -3.4e38f;
#pragma unroll
  for (int j = 0; j < E_NUM; j++) { if (j != i0 && l[j] > b1) { b1 = l[j]; i1 = j; } }
  float e1 = expf(b1 - b0);
  float d = 1.f + e1;
  tk_id[2 * t] = i0; tk_id[2 * t + 1] = i1;
  tk_w[2 * t] = 1.f / d; tk_w[2 * t + 1] = e1 / d;
  atomicAdd(&cnt[i0], 1);
  atomicAdd(&cnt[i1], 1);
}

__global__ void offsets_k(const int* __restrict__ cnt, int* __restrict__ offs) {
  if (threadIdx.x == 0 && blockIdx.x == 0) {
    int s = 0;
#pragma unroll
    for (int e = 0; e < E_NUM; e++) { offs[e] = s; s += cnt[e]; }
    offs[E_NUM] = s;
  }
}

// deterministic ordered compaction: block e scans tokens in order
__global__ __launch_bounds__(256) void scatter_k(const int* __restrict__ tk_id,
                                                 const float* __restrict__ tk_w,
                                                 const int* __restrict__ offs,
                                                 int* __restrict__ pair_tok,
                                                 float* __restrict__ pair_w,
                                                 int* __restrict__ pair_e,
                                                 int* __restrict__ pairidx) {
  int e = blockIdx.x;
  int tid = threadIdx.x, lane = tid & 63, wid = tid >> 6;
  __shared__ int wsum[4];
  int run = offs[e];
  for (int c = 0; c < T_TOK; c += 256) {
    int t = c + tid;
    int sel = -1;
    if (tk_id[2 * t] == e) sel = 0;
    else if (tk_id[2 * t + 1] == e) sel = 1;
    unsigned long long m = __ballot(sel >= 0);
    int rank = __popcll(m & ((1ull << lane) - 1ull));
    if (lane == 0) wsum[wid] = __popcll(m);
    __syncthreads();
    int wbase = 0;
#pragma unroll
    for (int j = 0; j < 4; j++) { if (j < wid) wbase += wsum[j]; }
    if (sel >= 0) {
      int p = run + wbase + rank;
      pair_tok[p] = t;
      pair_w[p] = tk_w[2 * t + sel];
      pair_e[p] = e;
      pairidx[2 * t + sel] = p;
    }
    run += wsum[0] + wsum[1] + wsum[2] + wsum[3];
    __syncthreads();
  }
}

// ---------- per-expert amax over |w| ----------
__global__ __launch_bounds__(256) void amax_k(const float* __restrict__ w,
                                              unsigned* __restrict__ amax_bits,
                                              size_t per_e) {
  int e = blockIdx.y;
  const float4* src = (const float4*)(w + (size_t)e * per_e);
  size_t i0 = (size_t)blockIdx.x * 1024 + threadIdx.x;
  float m = 0.f;
#pragma unroll
  for (int i = 0; i < 4; i++) {
    float4 v = src[i0 + (size_t)i * 256];
    m = fmaxf(m, fmaxf(fmaxf(fabsf(v.x), fabsf(v.y)), fmaxf(fabsf(v.z), fabsf(v.w))));
  }
  for (int off = 32; off > 0; off >>= 1) m = fmaxf(m, __shfl_xor(m, off));
  __shared__ float wmax[4];
  int lane = threadIdx.x & 63, wid = threadIdx.x >> 6;
  if (lane == 0) wmax[wid] = m;
  __syncthreads();
  if (threadIdx.x == 0) {
    float mm = fmaxf(fmaxf(wmax[0], wmax[1]), fmaxf(wmax[2], wmax[3]));
    atomicMax(&amax_bits[e], __float_as_uint(mm));
  }
}

// ---------- per-pair activation quant: Xq[p,:] = bf16(fp8(x[t,:]/s13[e])) ----------
__global__ __launch_bounds__(256) void quantx_k(const float* __restrict__ x,
                                                const int* __restrict__ pair_tok,
                                                const int* __restrict__ pair_e,
                                                const float* __restrict__ s13,
                                                unsigned short* __restrict__ Xq) {
  int p = blockIdx.x;
  int t = pair_tok[p];
  float sc = s13[pair_e[p]];
  float4 v = ((const float4*)(x + (size_t)t * H_DIM))[threadIdx.x];
  float qa, qb, qc, qd;
  fp8_pair(v.x / sc, v.y / sc, qa, qb);
  fp8_pair(v.z / sc, v.w / sc, qc, qd);
  ushort4 r;
  r.x = bfbits(qa); r.y = bfbits(qb); r.z = bfbits(qc); r.w = bfbits(qd);
  ((ushort4*)(Xq + (size_t)p * H_DIM))[threadIdx.x] = r;
}

// ---------- GEMM1: [count x H] @ [64g+64u x H]^T, fused silu*mul + act quant ----------
__global__ __launch_bounds__(256) void gemm1_k(const float* __restrict__ w13,
                                               const unsigned short* __restrict__ Xq,
                                               unsigned short* __restrict__ H1,
                                               const int* __restrict__ cnt,
                                               const int* __restrict__ offs,
                                               const unsigned* __restrict__ amax13,
                                               const float* __restrict__ s13,
                                               const float* __restrict__ s2in) {
  const int e = blockIdx.z;
  const int count = cnt[e];
  const int m0 = blockIdx.y * 128;
  if (m0 >= count) return;
  const int nt = blockIdx.x;  // 0..43 -> 64 gate cols + 64 up cols
  const int base = offs[e];

  const float amax = __uint_as_float(amax13[e]);
  const float wscale = amax / 448.f;
  const float inv_w = 448.f / amax;
  const float gs = s13[e] * wscale;      // dequant scale for h
  const float inv_a2 = 1.f / s2in[e];    // act quant inv scale

  __shared__ __align__(16) unsigned short As[128][32];
  __shared__ __align__(16) unsigned short Bg[64][32];
  __shared__ __align__(16) unsigned short Bu[64][32];

  const int tid = threadIdx.x;
  const int lane = tid & 63;
  const int wid = tid >> 6;
  const int wm = wid >> 1;  // row half (64)
  const int wn = wid & 1;   // col half (32 of 64)

  f32x4 accg[4][2], accu[4][2];
#pragma unroll
  for (int i = 0; i < 4; i++)
#pragma unroll
    for (int j = 0; j < 2; j++) { accg[i][j] = (f32x4)0.f; accu[i][j] = (f32x4)0.f; }

  const float* Wg = w13 + (size_t)e * (2 * I_DIM) * H_DIM + (size_t)(nt * 64) * H_DIM;
  const float* Wu = Wg + (size_t)I_DIM * H_DIM;

  // A staging: 512 slots (row, 8-elem seg); this thread does slot tid and tid+256
  const int arow = tid >> 2, aseg = tid & 3;
  int pr0 = base + m0 + arow;       if (pr0 > PAIRS - 1) pr0 = PAIRS - 1;
  int pr1 = base + m0 + arow + 64;  if (pr1 > PAIRS - 1) pr1 = PAIRS - 1;
  const unsigned short* a_src0 = Xq + (size_t)pr0 * H_DIM + aseg * 8;
  const unsigned short* a_src1 = Xq + (size_t)pr1 * H_DIM + aseg * 8;

  // B staging: row = tid>>2 (0..63), seg = tid&3 (8 f32 each)
  const int brow = tid >> 2, bseg = tid & 3;
  const float* bg_src = Wg + (size_t)brow * H_DIM + bseg * 8;
  const float* bu_src = Wu + (size_t)brow * H_DIM + bseg * 8;

  const int fr = lane & 15, ks = lane >> 4;

  for (int k0 = 0; k0 < H_DIM; k0 += 32) {
    __syncthreads();
    *(u32x4*)(&As[arow][aseg * 8]) = *(const u32x4*)(a_src0 + k0);
    *(u32x4*)(&As[arow + 64][aseg * 8]) = *(const u32x4*)(a_src1 + k0);
    {
      float4 f0 = *(const float4*)(bg_src + k0);
      float4 f1 = *(const float4*)(bg_src + k0 + 4);
      unsigned short q[8];
      float qa, qb;
      fp8_pair(f0.x * inv_w, f0.y * inv_w, qa, qb); q[0] = bfbits(qa); q[1] = bfbits(qb);
      fp8_pair(f0.z * inv_w, f0.w * inv_w, qa, qb); q[2] = bfbits(qa); q[3] = bfbits(qb);
      fp8_pair(f1.x * inv_w, f1.y * inv_w, qa, qb); q[4] = bfbits(qa); q[5] = bfbits(qb);
      fp8_pair(f1.z * inv_w, f1.w * inv_w, qa, qb); q[6] = bfbits(qa); q[7] = bfbits(qb);
      *(u32x4*)(&Bg[brow][bseg * 8]) = *(const u32x4*)q;
      f0 = *(const float4*)(bu_src + k0);
      f1 = *(const float4*)(bu_src + k0 + 4);
      fp8_pair(f0.x * inv_w, f0.y * inv_w, qa, qb); q[0] = bfbits(qa); q[1] = bfbits(qb);
      fp8_pair(f0.z * inv_w, f0.w * inv_w, qa, qb); q[2] = bfbits(qa); q[3] = bfbits(qb);
      fp8_pair(f1.x * inv_w, f1.y * inv_w, qa, qb); q[4] = bfbits(qa); q[5] = bfbits(qb);
      fp8_pair(f1.z * inv_w, f1.w * inv_w, qa, qb); q[6] = bfbits(qa); q[7] = bfbits(qb);
      *(u32x4*)(&Bu[brow][bseg * 8]) = *(const u32x4*)q;
    }
    __syncthreads();

    short8v a[4], bg2[2], bu2[2];
#pragma unroll
    for (int mi = 0; mi < 4; mi++)
      a[mi] = *(const short8v*)(&As[wm * 64 + mi * 16 + fr][ks * 8]);
#pragma unroll
    for (int ni = 0; ni < 2; ni++) {
      bg2[ni] = *(const short8v*)(&Bg[wn * 32 + ni * 16 + fr][ks * 8]);
      bu2[ni] = *(const short8v*)(&Bu[wn * 32 + ni * 16 + fr][ks * 8]);
    }
#pragma unroll
    for (int mi = 0; mi < 4; mi++)
#pragma unroll
      for (int ni = 0; ni < 2; ni++) {
        accg[mi][ni] = __builtin_amdgcn_mfma_f32_16x16x32_bf16(a[mi], bg2[ni], accg[mi][ni], 0, 0, 0);
        accu[mi][ni] = __builtin_amdgcn_mfma_f32_16x16x32_bf16(a[mi], bu2[ni], accu[mi][ni], 0, 0, 0);
      }
  }

  // epilogue: C row = (lane>>4)*4 + reg, col = lane&15
  const int rg = lane >> 4;
#pragma unroll
  for (int mi = 0; mi < 4; mi++) {
#pragma unroll
    for (int rr = 0; rr < 4; rr++) {
      int lrow = wm * 64 + mi * 16 + rg * 4 + rr;
      if (m0 + lrow < count) {
        size_t p = (size_t)(base + m0 + lrow);
#pragma unroll
        for (int ni = 0; ni < 2; ni++) {
          int col = nt * 64 + wn * 32 + ni * 16 + fr;
          float g = accg[mi][ni][rr] * gs;
          float u = accu[mi][ni][rr] * gs;
          float act = g / (1.f + expf(-g)) * u;
          float qa = fp8_one(act * inv_a2);
          H1[p * I_DIM + col] = bfbits(qa);
        }
      }
    }
  }
}

// ---------- GEMM2: [count x I] @ [128 x I]^T -> O[p, n] (or atomic to out) ----------
template <bool ATOMIC>
__global__ __launch_bounds__(256) void gemm2_k(const float* __restrict__ w2,
                                               const unsigned short* __restrict__ H1,
                                               float* __restrict__ O,
                                               float* __restrict__ out,
                                               const int* __restrict__ cnt,
                                               const int* __restrict__ offs,
                                               const unsigned* __restrict__ amax2,
                                               const float* __restrict__ s2in,
                                               const int* __restrict__ pair_tok,
                                               const float* __restrict__ pair_w) {
  const int e = blockIdx.z;
  const int count = cnt[e];
  const int m0 = blockIdx.y * 128;
  if (m0 >= count) return;
  const int n0 = blockIdx.x * 128;
  const int base = offs[e];

  const float amax = __uint_as_float(amax2[e]);
  const float wscale = amax / 448.f;
  const float inv_w = 448.f / amax;
  const float s2 = s2in[e] * wscale;

  __shared__ __align__(16) unsigned short As[128][32];
  __shared__ __align__(16) unsigned short Bs[128][32];

  const int tid = threadIdx.x;
  const int lane = tid & 63;
  const int wid = tid >> 6;
  const int wm = wid >> 1, wn = wid & 1;

  f32x4 acc[4][4];
#pragma unroll
  for (int i = 0; i < 4; i++)
#pragma unroll
    for (int j = 0; j < 4; j++) acc[i][j] = (f32x4)0.f;

  const float* W = w2 + (size_t)e * H_DIM * I_DIM + (size_t)n0 * I_DIM;

  const int arow = tid >> 2, aseg = tid & 3;
  int pr0 = base + m0 + arow;       if (pr0 > PAIRS - 1) pr0 = PAIRS - 1;
  int pr1 = base + m0 + arow + 64;  if (pr1 > PAIRS - 1) pr1 = PAIRS - 1;
  const unsigned short* a_src0 = H1 + (size_t)pr0 * I_DIM + aseg * 8;
  const unsigned short* a_src1 = H1 + (size_t)pr1 * I_DIM + aseg * 8;

  const int brow = tid >> 1, kh = tid & 1;
  const float* b_src = W + (size_t)brow * I_DIM + kh * 16;

  const int fr = lane & 15, ks = lane >> 4;

  for (int k0 = 0; k0 < I_DIM; k0 += 32) {
    __syncthreads();
    *(u32x4*)(&As[arow][aseg * 8]) = *(const u32x4*)(a_src0 + k0);
    *(u32x4*)(&As[arow + 64][aseg * 8]) = *(const u32x4*)(a_src1 + k0);
    {
      float4 f0 = *(const float4*)(b_src + k0);
      float4 f1 = *(const float4*)(b_src + k0 + 4);
      float4 f2 = *(const float4*)(b_src + k0 + 8);
      float4 f3 = *(const float4*)(b_src + k0 + 12);
      unsigned short q[16];
      float qa, qb;
      fp8_pair(f0.x * inv_w, f0.y * inv_w, qa, qb); q[0] = bfbits(qa); q[1] = bfbits(qb);
      fp8_pair(f0.z * inv_w, f0.w * inv_w, qa, qb); q[2] = bfbits(qa); q[3] = bfbits(qb);
      fp8_pair(f1.x * inv_w, f1.y * inv_w, qa, qb); q[4] = bfbits(qa); q[5] = bfbits(qb);
      fp8_pair(f1.z * inv_w, f1.w * inv_w, qa, qb); q[6] = bfbits(qa); q[7] = bfbits(qb);
      fp8_pair(f2.x * inv_w, f2.y * inv_w, qa, qb); q[8] = bfbits(qa); q[9] = bfbits(qb);
      fp8_pair(f2.z * inv_w, f2.w * inv_w, qa, qb); q[10] = bfbits(qa); q[11] = bfbits(qb);
      fp8_pair(f3.x * inv_w, f3.y * inv_w, qa, qb); q[12] = bfbits(qa); q[13] = bfbits(qb);
      fp8_pair(f3.z * inv_w, f3.w * inv_w, qa, qb); q[14] = bfbits(qa); q[15] = bfbits(qb);
      *(u32x4*)(&Bs[brow][kh * 16]) = *(const u32x4*)q;
      *(u32x4*)(&Bs[brow][kh * 16 + 8]) = *(const u32x4*)(q + 8);
    }
    __syncthreads();

    short8v a[4], b[4];
#pragma unroll
    for (int mi = 0; mi < 4; mi++)
      a[mi] = *(const short8v*)(&As[wm * 64 + mi * 16 + fr][ks * 8]);
#pragma unroll
    for (int ni = 0; ni < 4; ni++)
      b[ni] = *(const short8v*)(&Bs[wn * 64 + ni * 16 + fr][ks * 8]);
#pragma unroll
    for (int mi = 0; mi < 4; mi++)
#pragma unroll
      for (int ni = 0; ni < 4; ni++)
        acc[mi][ni] = __builtin_amdgcn_mfma_f32_16x16x32_bf16(a[mi], b[ni], acc[mi][ni], 0, 0, 0);
  }

  const int rg = lane >> 4;
#pragma unroll
  for (int mi = 0; mi < 4; mi++) {
#pragma unroll
    for (int rr = 0; rr < 4; rr++) {
      int lrow = wm * 64 + mi * 16 + rg * 4 + rr;
      if (m0 + lrow < count) {
        size_t p = (size_t)(base + m0 + lrow);
        int t = pair_tok[p];
        float pw = pair_w[p];
#pragma unroll
        for (int ni = 0; ni < 4; ni++) {
          int col = n0 + wn * 64 + ni * 16 + fr;
          float val = acc[mi][ni][rr] * s2;
          if (ATOMIC) {
            atomicAdd(&out[(size_t)t * H_DIM + col], val * pw);
          } else {
            O[p * H_DIM + col] = val * pw;
          }
        }
      }
    }
  }
}

// ---------- combine: out[t,:] = O[p0,:] + O[p1,:] (weights already folded in) ----------
__global__ __launch_bounds__(256) void combine_k(const float* __restrict__ O,
                                                 const int* __restrict__ pairidx,
                                                 float* __restrict__ out) {
  int t = blockIdx.x;
  int p0 = pairidx[2 * t], p1 = pairidx[2 * t + 1];
  float4 a = ((const float4*)(O + (size_t)p0 * H_DIM))[threadIdx.x];
  float4 b = ((const float4*)(O + (size_t)p1 * H_DIM))[threadIdx.x];
  float4 r;
  r.x = a.x + b.x; r.y = a.y + b.y; r.z = a.z + b.z; r.w = a.w + b.w;
  ((float4*)(out + (size_t)t * H_DIM))[threadIdx.x] = r;
}

extern "C" void kernel_launch(void* const* d_in, const int* in_sizes, int n_in,
                              void* d_out, int out_size, void* d_ws, size_t ws_size,
                              hipStream_t stream) {
  (void)in_sizes; (void)n_in; (void)out_size;
  const float* x      = (const float*)d_in[0];
  const float* logits = (const float*)d_in[1];
  const float* w13    = (const float*)d_in[2];
  const float* w2     = (const float*)d_in[3];
  const float* s13    = (const float*)d_in[4];
  const float* s2in   = (const float*)d_in[5];
  float* out = (float*)d_out;

  char* ws = (char*)d_ws;
  unsigned* amax13 = (unsigned*)(ws + 0);
  unsigned* amax2  = (unsigned*)(ws + 64);
  int* cnt     = (int*)(ws + 128);
  int* offs    = (int*)(ws + 192);
  int* tk_id   = (int*)(ws + 1024);
  float* tk_w  = (float*)(ws + 9216);
  int* pair_tok = (int*)(ws + 17408);
  float* pair_w = (float*)(ws + 25600);
  int* pair_e   = (int*)(ws + 33792);
  int* pairidx  = (int*)(ws + 41984);
  unsigned short* Xq = (unsigned short*)(ws + (size_t)(1 << 20));        // 4 MB
  unsigned short* H1 = (unsigned short*)(ws + (size_t)6 * (1 << 20));    // 11.5 MB
  float* O           = (float*)(ws + (size_t)18 * (1 << 20));            // 8 MB

  hipMemsetAsync(ws, 0, 4096, stream);

  routing_k<<<T_TOK / 256, 256, 0, stream>>>(logits, tk_id, tk_w, cnt);
  offsets_k<<<1, 64, 0, stream>>>(cnt, offs);
  scatter_k<<<E_NUM, 256, 0, stream>>>(tk_id, tk_w, offs, pair_tok, pair_w, pair_e, pairidx);

  // amax over weights: w13 per-expert 2*I*H=5767168 f32 -> 1408 blocks of 4096; w2 -> 704
  amax_k<<<dim3(1408, E_NUM), 256, 0, stream>>>(w13, amax13, (size_t)2 * I_DIM * H_DIM);
  amax_k<<<dim3(704, E_NUM), 256, 0, stream>>>(w2, amax2, (size_t)H_DIM * I_DIM);

  quantx_k<<<PAIRS, 256, 0, stream>>>(x, pair_tok, pair_e, s13, Xq);

  gemm1_k<<<dim3(I_DIM / 64, T_TOK / 128, E_NUM), 256, 0, stream>>>(
      w13, Xq, H1, cnt, offs, amax13, s13, s2in);

  size_t need_full = (size_t)18 * (1 << 20) + (size_t)PAIRS * H_DIM * 4;
  if (ws_size >= need_full) {
    gemm2_k<false><<<dim3(H_DIM / 128, T_TOK / 128, E_NUM), 256, 0, stream>>>(
        w2, H1, O, out, cnt, offs, amax2, s2in, pair_tok, pair_w);
    combine_k<<<T_TOK, 256, 0, stream>>>(O, pairidx, out);
  } else {
    hipMemsetAsync(out, 0, (size_t)T_TOK * H_DIM * 4, stream);
    gemm2_k<true><<<dim3(H_DIM / 128, T_TOK / 128, E_NUM), 256, 0, stream>>>(
        w2, H1, out, out, cnt, offs, amax2, s2in, pair_tok, pair_w);
  }
}

// Round 2
// 264.200 us; speedup vs baseline: 1.7376x; 1.7376x over previous
//
#include <hip/hip_runtime.h>
#include <cstdint>
#include <cstddef>

#define T_TOK 1024
#define H_DIM 1024
#define I_DIM 2816
#define E_NUM 8
#define PAIRS 2048  // T_TOK * top_k(=2)

typedef __attribute__((ext_vector_type(4))) float f32x4;
typedef __attribute__((ext_vector_type(4))) unsigned int u32x4;
typedef long i64;

// ---------- fp8 e4m3fn encode ----------
__device__ __forceinline__ unsigned char fp8e4m3_sw(float v) {
  v = fminf(448.f, fmaxf(-448.f, v));
  unsigned b = __float_as_uint(v);
  unsigned s = (b >> 24) & 0x80u;
  float a = fabsf(v);
  if (a < 0.015625f) {  // subnormal range, step 2^-9
    int m = (int)rintf(a * 512.f);
    return (unsigned char)(s | (unsigned)m);
  }
  unsigned ab = b & 0x7fffffffu;
  unsigned rnd = 0x7FFFFu + ((ab >> 20) & 1u);
  ab += rnd;
  int e = (int)(ab >> 23) - 127;
  unsigned m = (ab >> 20) & 7u;
  if (e > 8 || (e == 8 && m > 6)) { e = 8; m = 6; }
  return (unsigned char)(s | (unsigned)((e + 7) << 3) | m);
}

// pack 4 f32 -> 4 fp8 bytes (RNE, saturating)
__device__ __forceinline__ unsigned q4(float a, float b, float c, float d) {
#if __has_builtin(__builtin_amdgcn_cvt_pk_fp8_f32)
  unsigned w = (unsigned)__builtin_amdgcn_cvt_pk_fp8_f32(a, b, 0, false);
  return (unsigned)__builtin_amdgcn_cvt_pk_fp8_f32(c, d, (int)w, true);
#else
  return (unsigned)fp8e4m3_sw(a) | ((unsigned)fp8e4m3_sw(b) << 8) |
         ((unsigned)fp8e4m3_sw(c) << 16) | ((unsigned)fp8e4m3_sw(d) << 24);
#endif
}

__device__ __forceinline__ unsigned char q1(float a) {
#if __has_builtin(__builtin_amdgcn_cvt_pk_fp8_f32)
  return (unsigned char)((unsigned)__builtin_amdgcn_cvt_pk_fp8_f32(a, a, 0, false) & 0xFFu);
#else
  return fp8e4m3_sw(a);
#endif
}

// ---------- routing: softmax -> top2 -> renorm ----------
__global__ __launch_bounds__(256) void routing_k(const float* __restrict__ logits,
                                                 int* __restrict__ tk_id,
                                                 float* __restrict__ tk_w,
                                                 int* __restrict__ cnt) {
  int t = blockIdx.x * 256 + threadIdx.x;
  if (t >= T_TOK) return;
  float l[E_NUM];
#pragma unroll
  for (int j = 0; j < E_NUM; j++) l[j] = logits[t * E_NUM + j];
  int i0 = 0; float b0 = l[0];
#pragma unroll
  for (int j = 1; j < E_NUM; j++) { if (l[j] > b0) { b0 = l[j]; i0 = j; } }
  int i1 = -1; float b1 = -3.4e38f;
#pragma unroll
  for (int j = 0; j < E_NUM; j++) { if (j != i0 && l[j] > b1) { b1 = l[j]; i1 = j; } }
  float e1 = expf(b1 - b0);
  float d = 1.f + e1;
  tk_id[2 * t] = i0; tk_id[2 * t + 1] = i1;
  tk_w[2 * t] = 1.f / d; tk_w[2 * t + 1] = e1 / d;
  atomicAdd(&cnt[i0], 1);
  atomicAdd(&cnt[i1], 1);
}

__global__ void offsets_k(const int* __restrict__ cnt, int* __restrict__ offs) {
  if (threadIdx.x == 0 && blockIdx.x == 0) {
    int s = 0;
#pragma unroll
    for (int e = 0; e < E_NUM; e++) { offs[e] = s; s += cnt[e]; }
    offs[E_NUM] = s;
  }
}

__global__ __launch_bounds__(256) void scatter_k(const int* __restrict__ tk_id,
                                                 const float* __restrict__ tk_w,
                                                 const int* __restrict__ offs,
                                                 int* __restrict__ pair_tok,
                                                 float* __restrict__ pair_w,
                                                 int* __restrict__ pairidx) {
  int e = blockIdx.x;
  int tid = threadIdx.x, lane = tid & 63, wid = tid >> 6;
  __shared__ int wsum[4];
  int run = offs[e];
  for (int c = 0; c < T_TOK; c += 256) {
    int t = c + tid;
    int sel = -1;
    if (tk_id[2 * t] == e) sel = 0;
    else if (tk_id[2 * t + 1] == e) sel = 1;
    unsigned long long m = __ballot(sel >= 0);
    int rank = __popcll(m & ((1ull << lane) - 1ull));
    if (lane == 0) wsum[wid] = __popcll(m);
    __syncthreads();
    int wbase = 0;
#pragma unroll
    for (int j = 0; j < 4; j++) { if (j < wid) wbase += wsum[j]; }
    if (sel >= 0) {
      int p = run + wbase + rank;
      pair_tok[p] = t;
      pair_w[p] = tk_w[2 * t + sel];
      pairidx[2 * t + sel] = p;
    }
    run += wsum[0] + wsum[1] + wsum[2] + wsum[3];
    __syncthreads();
  }
}

// ---------- per-expert amax: grid-stride, ONE atomic per block ----------
__global__ __launch_bounds__(256) void amax_k(const float* __restrict__ w,
                                              unsigned* __restrict__ amax_bits,
                                              int nf4_per_e, int iters) {
  int e = blockIdx.y;
  const float4* src = (const float4*)w + (size_t)e * nf4_per_e;
  int idx = blockIdx.x * 256 + threadIdx.x;
  int stride = gridDim.x * 256;
  float m = 0.f;
  for (int j = 0; j < iters; j += 4) {
    float4 v0 = src[idx + (size_t)(j + 0) * stride];
    float4 v1 = src[idx + (size_t)(j + 1) * stride];
    float4 v2 = src[idx + (size_t)(j + 2) * stride];
    float4 v3 = src[idx + (size_t)(j + 3) * stride];
    m = fmaxf(m, fmaxf(fmaxf(fabsf(v0.x), fabsf(v0.y)), fmaxf(fabsf(v0.z), fabsf(v0.w))));
    m = fmaxf(m, fmaxf(fmaxf(fabsf(v1.x), fabsf(v1.y)), fmaxf(fabsf(v1.z), fabsf(v1.w))));
    m = fmaxf(m, fmaxf(fmaxf(fabsf(v2.x), fabsf(v2.y)), fmaxf(fabsf(v2.z), fabsf(v2.w))));
    m = fmaxf(m, fmaxf(fmaxf(fabsf(v3.x), fabsf(v3.y)), fmaxf(fabsf(v3.z), fabsf(v3.w))));
  }
#pragma unroll
  for (int off = 32; off > 0; off >>= 1) m = fmaxf(m, __shfl_xor(m, off));
  __shared__ float wmax[4];
  int lane = threadIdx.x & 63, wid = threadIdx.x >> 6;
  if (lane == 0) wmax[wid] = m;
  __syncthreads();
  if (threadIdx.x == 0) {
    float mm = fmaxf(fmaxf(wmax[0], wmax[1]), fmaxf(wmax[2], wmax[3]));
    atomicMax(&amax_bits[e], __float_as_uint(mm));
  }
}

// ---------- per-pair activation quant: Xq[p,k] = fp8(x[t,k]/s13[e]) bytes ----------
__global__ __launch_bounds__(256) void quantx_k(const float* __restrict__ x,
                                                const int* __restrict__ pair_tok,
                                                const int* __restrict__ pair_e_offs,
                                                const float* __restrict__ s13,
                                                unsigned char* __restrict__ Xq) {
  int p = blockIdx.x;
  int t = pair_tok[p];
  // recover expert from offs (small linear scan, E=8)
  int e = 0;
#pragma unroll
  for (int j = 1; j < E_NUM; j++) { if (p >= pair_e_offs[j]) e = j; }
  float inv = 1.f / s13[e];
  float4 v = ((const float4*)(x + (size_t)t * H_DIM))[threadIdx.x];
  float a = fminf(448.f, fmaxf(-448.f, v.x * inv));
  float b = fminf(448.f, fmaxf(-448.f, v.y * inv));
  float c = fminf(448.f, fmaxf(-448.f, v.z * inv));
  float d = fminf(448.f, fmaxf(-448.f, v.w * inv));
  ((unsigned*)(Xq + (size_t)p * H_DIM))[threadIdx.x] = q4(a, b, c, d);
}

// ---------- GEMM1: fp8 MFMA, [count x H] @ [64g+64u x H]^T, fused silu*mul + quant ----------
__global__ __launch_bounds__(256) void gemm1_k(const float* __restrict__ w13,
                                               const unsigned char* __restrict__ Xq,
                                               unsigned char* __restrict__ H1,
                                               const int* __restrict__ cnt,
                                               const int* __restrict__ offs,
                                               const unsigned* __restrict__ amax13,
                                               const float* __restrict__ s13,
                                               const float* __restrict__ s2in) {
  const int e = blockIdx.z;
  const int count = cnt[e];
  const int m0 = blockIdx.y * 128;
  if (m0 >= count) return;
  const int nt = blockIdx.x;
  const int base = offs[e];

  const float amax = __uint_as_float(amax13[e]);
  const float inv_w = 448.f / amax;
  const float gs = s13[e] * (amax / 448.f);
  const float inv_a2 = 1.f / s2in[e];

  __shared__ __align__(16) unsigned char As[128][80];
  __shared__ __align__(16) unsigned char Bg[64][80];
  __shared__ __align__(16) unsigned char Bu[64][80];

  const int tid = threadIdx.x, lane = tid & 63, wid = tid >> 6;
  const int wm = wid >> 1, wn = wid & 1;
  const int fr = lane & 15, ks = lane >> 4;

  f32x4 accg[4][2], accu[4][2];
#pragma unroll
  for (int i = 0; i < 4; i++)
#pragma unroll
    for (int j = 0; j < 2; j++) { accg[i][j] = (f32x4)0.f; accu[i][j] = (f32x4)0.f; }

  const float* Wg = w13 + (size_t)e * (2 * I_DIM) * H_DIM + (size_t)(nt * 64) * H_DIM;
  const float* Wu = Wg + (size_t)I_DIM * H_DIM;

  const int arow = tid >> 2, aseg = tid & 3;  // A: 128 rows x 64B, 4 segs of 16B
  int pr0 = base + m0 + arow;       if (pr0 > PAIRS - 1) pr0 = PAIRS - 1;
  int pr1 = base + m0 + arow + 64;  if (pr1 > PAIRS - 1) pr1 = PAIRS - 1;
  const unsigned char* a0 = Xq + (size_t)pr0 * H_DIM + aseg * 16;
  const unsigned char* a1 = Xq + (size_t)pr1 * H_DIM + aseg * 16;

  const int brow = tid >> 2, bseg = tid & 3;  // B: 64 rows, seg of 16 f32 -> 16 fp8 B
  const float* bg = Wg + (size_t)brow * H_DIM + bseg * 16;
  const float* bu = Wu + (size_t)brow * H_DIM + bseg * 16;

  for (int k0 = 0; k0 < H_DIM; k0 += 64) {
    __syncthreads();
    *(u32x4*)&As[arow][aseg * 16]      = *(const u32x4*)(a0 + k0);
    *(u32x4*)&As[arow + 64][aseg * 16] = *(const u32x4*)(a1 + k0);
    {
      const float4* pg = (const float4*)(bg + k0);
      float4 f0 = pg[0], f1 = pg[1], f2 = pg[2], f3 = pg[3];
      u32x4 qv;
      qv.x = q4(f0.x * inv_w, f0.y * inv_w, f0.z * inv_w, f0.w * inv_w);
      qv.y = q4(f1.x * inv_w, f1.y * inv_w, f1.z * inv_w, f1.w * inv_w);
      qv.z = q4(f2.x * inv_w, f2.y * inv_w, f2.z * inv_w, f2.w * inv_w);
      qv.w = q4(f3.x * inv_w, f3.y * inv_w, f3.z * inv_w, f3.w * inv_w);
      *(u32x4*)&Bg[brow][bseg * 16] = qv;
      const float4* pu = (const float4*)(bu + k0);
      f0 = pu[0]; f1 = pu[1]; f2 = pu[2]; f3 = pu[3];
      qv.x = q4(f0.x * inv_w, f0.y * inv_w, f0.z * inv_w, f0.w * inv_w);
      qv.y = q4(f1.x * inv_w, f1.y * inv_w, f1.z * inv_w, f1.w * inv_w);
      qv.z = q4(f2.x * inv_w, f2.y * inv_w, f2.z * inv_w, f2.w * inv_w);
      qv.w = q4(f3.x * inv_w, f3.y * inv_w, f3.z * inv_w, f3.w * inv_w);
      *(u32x4*)&Bu[brow][bseg * 16] = qv;
    }
    __syncthreads();

    i64 a[4][2], vg[2][2], vu[2][2];
#pragma unroll
    for (int mi = 0; mi < 4; mi++)
#pragma unroll
      for (int ksl = 0; ksl < 2; ksl++)
        a[mi][ksl] = *(const i64*)&As[wm * 64 + mi * 16 + fr][ksl * 32 + ks * 8];
#pragma unroll
    for (int ni = 0; ni < 2; ni++)
#pragma unroll
      for (int ksl = 0; ksl < 2; ksl++) {
        vg[ni][ksl] = *(const i64*)&Bg[wn * 32 + ni * 16 + fr][ksl * 32 + ks * 8];
        vu[ni][ksl] = *(const i64*)&Bu[wn * 32 + ni * 16 + fr][ksl * 32 + ks * 8];
      }
#pragma unroll
    for (int mi = 0; mi < 4; mi++)
#pragma unroll
      for (int ni = 0; ni < 2; ni++)
#pragma unroll
        for (int ksl = 0; ksl < 2; ksl++) {
          accg[mi][ni] = __builtin_amdgcn_mfma_f32_16x16x32_fp8_fp8(a[mi][ksl], vg[ni][ksl], accg[mi][ni], 0, 0, 0);
          accu[mi][ni] = __builtin_amdgcn_mfma_f32_16x16x32_fp8_fp8(a[mi][ksl], vu[ni][ksl], accu[mi][ni], 0, 0, 0);
        }
  }

  const int rg = lane >> 4;
#pragma unroll
  for (int mi = 0; mi < 4; mi++) {
#pragma unroll
    for (int rr = 0; rr < 4; rr++) {
      int lrow = wm * 64 + mi * 16 + rg * 4 + rr;
      if (m0 + lrow < count) {
        size_t p = (size_t)(base + m0 + lrow);
#pragma unroll
        for (int ni = 0; ni < 2; ni++) {
          int col = nt * 64 + wn * 32 + ni * 16 + fr;
          float g = accg[mi][ni][rr] * gs;
          float u = accu[mi][ni][rr] * gs;
          float act = g / (1.f + expf(-g)) * u * inv_a2;
          act = fminf(448.f, fmaxf(-448.f, act));
          H1[p * I_DIM + col] = q1(act);
        }
      }
    }
  }
}

// ---------- GEMM2: fp8 MFMA, [count x I] @ [128 x I]^T ----------
template <bool ATOMIC>
__global__ __launch_bounds__(256) void gemm2_k(const float* __restrict__ w2,
                                               const unsigned char* __restrict__ H1,
                                               float* __restrict__ O,
                                               float* __restrict__ out,
                                               const int* __restrict__ cnt,
                                               const int* __restrict__ offs,
                                               const unsigned* __restrict__ amax2,
                                               const float* __restrict__ s2in,
                                               const int* __restrict__ pair_tok,
                                               const float* __restrict__ pair_w) {
  const int e = blockIdx.z;
  const int count = cnt[e];
  const int m0 = blockIdx.y * 128;
  if (m0 >= count) return;
  const int n0 = blockIdx.x * 128;
  const int base = offs[e];

  const float amax = __uint_as_float(amax2[e]);
  const float inv_w = 448.f / amax;
  const float s2 = s2in[e] * (amax / 448.f);

  __shared__ __align__(16) unsigned char As[128][80];
  __shared__ __align__(16) unsigned char Bs[128][80];

  const int tid = threadIdx.x, lane = tid & 63, wid = tid >> 6;
  const int wm = wid >> 1, wn = wid & 1;
  const int fr = lane & 15, ks = lane >> 4;

  f32x4 acc[4][4];
#pragma unroll
  for (int i = 0; i < 4; i++)
#pragma unroll
    for (int j = 0; j < 4; j++) acc[i][j] = (f32x4)0.f;

  const float* W = w2 + (size_t)e * H_DIM * I_DIM + (size_t)n0 * I_DIM;

  const int arow = tid >> 2, aseg = tid & 3;
  int pr0 = base + m0 + arow;       if (pr0 > PAIRS - 1) pr0 = PAIRS - 1;
  int pr1 = base + m0 + arow + 64;  if (pr1 > PAIRS - 1) pr1 = PAIRS - 1;
  const unsigned char* a0 = H1 + (size_t)pr0 * I_DIM + aseg * 16;
  const unsigned char* a1 = H1 + (size_t)pr1 * I_DIM + aseg * 16;

  const int brow = tid >> 2, bseg = tid & 3;
  const float* b0 = W + (size_t)brow * I_DIM + bseg * 16;
  const float* b1 = W + (size_t)(brow + 64) * I_DIM + bseg * 16;

  for (int k0 = 0; k0 < I_DIM; k0 += 64) {
    __syncthreads();
    *(u32x4*)&As[arow][aseg * 16]      = *(const u32x4*)(a0 + k0);
    *(u32x4*)&As[arow + 64][aseg * 16] = *(const u32x4*)(a1 + k0);
    {
      const float4* p0 = (const float4*)(b0 + k0);
      float4 f0 = p0[0], f1 = p0[1], f2 = p0[2], f3 = p0[3];
      u32x4 qv;
      qv.x = q4(f0.x * inv_w, f0.y * inv_w, f0.z * inv_w, f0.w * inv_w);
      qv.y = q4(f1.x * inv_w, f1.y * inv_w, f1.z * inv_w, f1.w * inv_w);
      qv.z = q4(f2.x * inv_w, f2.y * inv_w, f2.z * inv_w, f2.w * inv_w);
      qv.w = q4(f3.x * inv_w, f3.y * inv_w, f3.z * inv_w, f3.w * inv_w);
      *(u32x4*)&Bs[brow][bseg * 16] = qv;
      const float4* p1 = (const float4*)(b1 + k0);
      f0 = p1[0]; f1 = p1[1]; f2 = p1[2]; f3 = p1[3];
      qv.x = q4(f0.x * inv_w, f0.y * inv_w, f0.z * inv_w, f0.w * inv_w);
      qv.y = q4(f1.x * inv_w, f1.y * inv_w, f1.z * inv_w, f1.w * inv_w);
      qv.z = q4(f2.x * inv_w, f2.y * inv_w, f2.z * inv_w, f2.w * inv_w);
      qv.w = q4(f3.x * inv_w, f3.y * inv_w, f3.z * inv_w, f3.w * inv_w);
      *(u32x4*)&Bs[brow + 64][bseg * 16] = qv;
    }
    __syncthreads();

    i64 a[4][2], b[4][2];
#pragma unroll
    for (int mi = 0; mi < 4; mi++)
#pragma unroll
      for (int ksl = 0; ksl < 2; ksl++)
        a[mi][ksl] = *(const i64*)&As[wm * 64 + mi * 16 + fr][ksl * 32 + ks * 8];
#pragma unroll
    for (int ni = 0; ni < 4; ni++)
#pragma unroll
      for (int ksl = 0; ksl < 2; ksl++)
        b[ni][ksl] = *(const i64*)&Bs[wn * 64 + ni * 16 + fr][ksl * 32 + ks * 8];
#pragma unroll
    for (int mi = 0; mi < 4; mi++)
#pragma unroll
      for (int ni = 0; ni < 4; ni++)
#pragma unroll
        for (int ksl = 0; ksl < 2; ksl++)
          acc[mi][ni] = __builtin_amdgcn_mfma_f32_16x16x32_fp8_fp8(a[mi][ksl], b[ni][ksl], acc[mi][ni], 0, 0, 0);
  }

  const int rg = lane >> 4;
#pragma unroll
  for (int mi = 0; mi < 4; mi++) {
#pragma unroll
    for (int rr = 0; rr < 4; rr++) {
      int lrow = wm * 64 + mi * 16 + rg * 4 + rr;
      if (m0 + lrow < count) {
        size_t p = (size_t)(base + m0 + lrow);
        int t = pair_tok[p];
        float pw = pair_w[p];
#pragma unroll
        for (int ni = 0; ni < 4; ni++) {
          int col = n0 + wn * 64 + ni * 16 + fr;
          float val = acc[mi][ni][rr] * s2 * pw;
          if (ATOMIC) {
            atomicAdd(&out[(size_t)t * H_DIM + col], val);
          } else {
            O[p * H_DIM + col] = val;
          }
        }
      }
    }
  }
}

// ---------- combine ----------
__global__ __launch_bounds__(256) void combine_k(const float* __restrict__ O,
                                                 const int* __restrict__ pairidx,
                                                 float* __restrict__ out) {
  int t = blockIdx.x;
  int p0 = pairidx[2 * t], p1 = pairidx[2 * t + 1];
  float4 a = ((const float4*)(O + (size_t)p0 * H_DIM))[threadIdx.x];
  float4 b = ((const float4*)(O + (size_t)p1 * H_DIM))[threadIdx.x];
  float4 r;
  r.x = a.x + b.x; r.y = a.y + b.y; r.z = a.z + b.z; r.w = a.w + b.w;
  ((float4*)(out + (size_t)t * H_DIM))[threadIdx.x] = r;
}

extern "C" void kernel_launch(void* const* d_in, const int* in_sizes, int n_in,
                              void* d_out, int out_size, void* d_ws, size_t ws_size,
                              hipStream_t stream) {
  (void)in_sizes; (void)n_in; (void)out_size;
  const float* x      = (const float*)d_in[0];
  const float* logits = (const float*)d_in[1];
  const float* w13    = (const float*)d_in[2];
  const float* w2     = (const float*)d_in[3];
  const float* s13    = (const float*)d_in[4];
  const float* s2in   = (const float*)d_in[5];
  float* out = (float*)d_out;

  char* ws = (char*)d_ws;
  unsigned* amax13 = (unsigned*)(ws + 0);
  unsigned* amax2  = (unsigned*)(ws + 64);
  int* cnt     = (int*)(ws + 128);
  int* offs    = (int*)(ws + 192);
  int* tk_id   = (int*)(ws + 1024);
  float* tk_w  = (float*)(ws + 9216);
  int* pair_tok = (int*)(ws + 17408);
  float* pair_w = (float*)(ws + 25600);
  int* pairidx  = (int*)(ws + 33792);
  unsigned char* Xq = (unsigned char*)(ws + (size_t)(1 << 20));       // 2 MB
  unsigned char* H1 = (unsigned char*)(ws + (size_t)4 * (1 << 20));   // 5.77 MB
  float* O          = (float*)(ws + (size_t)10 * (1 << 20));          // 8 MB

  hipMemsetAsync(ws, 0, 4096, stream);

  routing_k<<<T_TOK / 256, 256, 0, stream>>>(logits, tk_id, tk_w, cnt);
  offsets_k<<<1, 64, 0, stream>>>(cnt, offs);
  scatter_k<<<E_NUM, 256, 0, stream>>>(tk_id, tk_w, offs, pair_tok, pair_w, pairidx);

  // amax: 64 blocks/expert, one atomic per block
  amax_k<<<dim3(64, E_NUM), 256, 0, stream>>>(w13, amax13, 2 * I_DIM * H_DIM / 4, 88);
  amax_k<<<dim3(64, E_NUM), 256, 0, stream>>>(w2, amax2, H_DIM * I_DIM / 4, 44);

  quantx_k<<<PAIRS, 256, 0, stream>>>(x, pair_tok, offs, s13, Xq);

  gemm1_k<<<dim3(I_DIM / 64, 16, E_NUM), 256, 0, stream>>>(
      w13, Xq, H1, cnt, offs, amax13, s13, s2in);

  size_t need_full = (size_t)10 * (1 << 20) + (size_t)PAIRS * H_DIM * 4;
  if (ws_size >= need_full) {
    gemm2_k<false><<<dim3(H_DIM / 128, 16, E_NUM), 256, 0, stream>>>(
        w2, H1, O, out, cnt, offs, amax2, s2in, pair_tok, pair_w);
    combine_k<<<T_TOK, 256, 0, stream>>>(O, pairidx, out);
  } else {
    hipMemsetAsync(out, 0, (size_t)T_TOK * H_DIM * 4, stream);
    gemm2_k<true><<<dim3(H_DIM / 128, 16, E_NUM), 256, 0, stream>>>(
        w2, H1, out, out, cnt, offs, amax2, s2in, pair_tok, pair_w);
  }
}

// Round 3
// 252.084 us; speedup vs baseline: 1.8211x; 1.0481x over previous
//
#include <hip/hip_runtime.h>
#include <cstdint>
#include <cstddef>

#define T_TOK 1024
#define H_DIM 1024
#define I_DIM 2816
#define E_NUM 8
#define PAIRS 2048  // T_TOK * top_k(=2)

typedef __attribute__((ext_vector_type(4))) float f32x4;
typedef __attribute__((ext_vector_type(4))) unsigned int u32x4;
typedef long i64;

// ---------- fp8 e4m3fn encode ----------
__device__ __forceinline__ unsigned char fp8e4m3_sw(float v) {
  v = fminf(448.f, fmaxf(-448.f, v));
  unsigned b = __float_as_uint(v);
  unsigned s = (b >> 24) & 0x80u;
  float a = fabsf(v);
  if (a < 0.015625f) {
    int m = (int)rintf(a * 512.f);
    return (unsigned char)(s | (unsigned)m);
  }
  unsigned ab = b & 0x7fffffffu;
  unsigned rnd = 0x7FFFFu + ((ab >> 20) & 1u);
  ab += rnd;
  int e = (int)(ab >> 23) - 127;
  unsigned m = (ab >> 20) & 7u;
  if (e > 8 || (e == 8 && m > 6)) { e = 8; m = 6; }
  return (unsigned char)(s | (unsigned)((e + 7) << 3) | m);
}

__device__ __forceinline__ unsigned q4(float a, float b, float c, float d) {
#if __has_builtin(__builtin_amdgcn_cvt_pk_fp8_f32)
  unsigned w = (unsigned)__builtin_amdgcn_cvt_pk_fp8_f32(a, b, 0, false);
  return (unsigned)__builtin_amdgcn_cvt_pk_fp8_f32(c, d, (int)w, true);
#else
  return (unsigned)fp8e4m3_sw(a) | ((unsigned)fp8e4m3_sw(b) << 8) |
         ((unsigned)fp8e4m3_sw(c) << 16) | ((unsigned)fp8e4m3_sw(d) << 24);
#endif
}

__device__ __forceinline__ unsigned char q1(float a) {
#if __has_builtin(__builtin_amdgcn_cvt_pk_fp8_f32)
  return (unsigned char)((unsigned)__builtin_amdgcn_cvt_pk_fp8_f32(a, a, 0, false) & 0xFFu);
#else
  return fp8e4m3_sw(a);
#endif
}

// ---------- init: zero control region (cnt, amax, offs) ----------
__global__ void init_k(unsigned* __restrict__ p) {
  p[blockIdx.x * 256 + threadIdx.x] = 0;  // grid 4 x 256 -> 4096 B
}

// ---------- routing ----------
__global__ __launch_bounds__(256) void routing_k(const float* __restrict__ logits,
                                                 int* __restrict__ tk_id,
                                                 float* __restrict__ tk_w,
                                                 int* __restrict__ cnt) {
  int t = blockIdx.x * 256 + threadIdx.x;
  if (t >= T_TOK) return;
  float l[E_NUM];
#pragma unroll
  for (int j = 0; j < E_NUM; j++) l[j] = logits[t * E_NUM + j];
  int i0 = 0; float b0 = l[0];
#pragma unroll
  for (int j = 1; j < E_NUM; j++) { if (l[j] > b0) { b0 = l[j]; i0 = j; } }
  int i1 = -1; float b1 = -3.4e38f;
#pragma unroll
  for (int j = 0; j < E_NUM; j++) { if (j != i0 && l[j] > b1) { b1 = l[j]; i1 = j; } }
  float e1 = expf(b1 - b0);
  float d = 1.f + e1;
  tk_id[2 * t] = i0; tk_id[2 * t + 1] = i1;
  tk_w[2 * t] = 1.f / d; tk_w[2 * t + 1] = e1 / d;
  atomicAdd(&cnt[i0], 1);
  atomicAdd(&cnt[i1], 1);
}

__global__ void offsets_k(const int* __restrict__ cnt, int* __restrict__ offs) {
  if (threadIdx.x == 0 && blockIdx.x == 0) {
    int s = 0;
#pragma unroll
    for (int e = 0; e < E_NUM; e++) { offs[e] = s; s += cnt[e]; }
    offs[E_NUM] = s;
  }
}

__global__ __launch_bounds__(256) void scatter_k(const int* __restrict__ tk_id,
                                                 const float* __restrict__ tk_w,
                                                 const int* __restrict__ offs,
                                                 int* __restrict__ pair_tok,
                                                 float* __restrict__ pair_w,
                                                 int* __restrict__ pairidx) {
  int e = blockIdx.x;
  int tid = threadIdx.x, lane = tid & 63, wid = tid >> 6;
  __shared__ int wsum[4];
  int run = offs[e];
  for (int c = 0; c < T_TOK; c += 256) {
    int t = c + tid;
    int sel = -1;
    if (tk_id[2 * t] == e) sel = 0;
    else if (tk_id[2 * t + 1] == e) sel = 1;
    unsigned long long m = __ballot(sel >= 0);
    int rank = __popcll(m & ((1ull << lane) - 1ull));
    if (lane == 0) wsum[wid] = __popcll(m);
    __syncthreads();
    int wbase = 0;
#pragma unroll
    for (int j = 0; j < 4; j++) { if (j < wid) wbase += wsum[j]; }
    if (sel >= 0) {
      int p = run + wbase + rank;
      pair_tok[p] = t;
      pair_w[p] = tk_w[2 * t + sel];
      pairidx[2 * t + sel] = p;
    }
    run += wsum[0] + wsum[1] + wsum[2] + wsum[3];
    __syncthreads();
  }
}

// ---------- per-expert amax (grid-stride, 1 atomic per block) ----------
__global__ __launch_bounds__(256) void amax_k(const float* __restrict__ w,
                                              unsigned* __restrict__ amax_bits,
                                              int nf4_per_e, int iters) {
  int e = blockIdx.y;
  const float4* src = (const float4*)w + (size_t)e * nf4_per_e;
  int idx = blockIdx.x * 256 + threadIdx.x;
  int stride = gridDim.x * 256;
  float m = 0.f;
  for (int j = 0; j < iters; j += 4) {
    float4 v0 = src[idx + (size_t)(j + 0) * stride];
    float4 v1 = src[idx + (size_t)(j + 1) * stride];
    float4 v2 = src[idx + (size_t)(j + 2) * stride];
    float4 v3 = src[idx + (size_t)(j + 3) * stride];
    m = fmaxf(m, fmaxf(fmaxf(fabsf(v0.x), fabsf(v0.y)), fmaxf(fabsf(v0.z), fabsf(v0.w))));
    m = fmaxf(m, fmaxf(fmaxf(fabsf(v1.x), fabsf(v1.y)), fmaxf(fabsf(v1.z), fabsf(v1.w))));
    m = fmaxf(m, fmaxf(fmaxf(fabsf(v2.x), fabsf(v2.y)), fmaxf(fabsf(v2.z), fabsf(v2.w))));
    m = fmaxf(m, fmaxf(fmaxf(fabsf(v3.x), fabsf(v3.y)), fmaxf(fabsf(v3.z), fabsf(v3.w))));
  }
#pragma unroll
  for (int off = 32; off > 0; off >>= 1) m = fmaxf(m, __shfl_xor(m, off));
  __shared__ float wmax[4];
  int lane = threadIdx.x & 63, wid = threadIdx.x >> 6;
  if (lane == 0) wmax[wid] = m;
  __syncthreads();
  if (threadIdx.x == 0) {
    float mm = fmaxf(fmaxf(wmax[0], wmax[1]), fmaxf(wmax[2], wmax[3]));
    atomicMax(&amax_bits[e], __float_as_uint(mm));
  }
}

// ---------- weight fp8 pre-quant (streaming) ----------
__global__ __launch_bounds__(256) void quantw_k(const float* __restrict__ w,
                                                unsigned char* __restrict__ wq,
                                                const unsigned* __restrict__ amax_bits,
                                                int n16_per_e, int iters) {
  int e = blockIdx.y;
  float inv = 448.f / __uint_as_float(amax_bits[e]);
  const float4* src = (const float4*)w + (size_t)e * n16_per_e * 4;
  u32x4* dst = (u32x4*)(wq + (size_t)e * n16_per_e * 16);
  int idx = blockIdx.x * 256 + threadIdx.x;
  int stride = gridDim.x * 256;
  for (int j = 0; j < iters; j++) {
    size_t u = idx + (size_t)j * stride;
    float4 f0 = src[4 * u], f1 = src[4 * u + 1], f2 = src[4 * u + 2], f3 = src[4 * u + 3];
    u32x4 qv;
    qv.x = q4(f0.x * inv, f0.y * inv, f0.z * inv, f0.w * inv);
    qv.y = q4(f1.x * inv, f1.y * inv, f1.z * inv, f1.w * inv);
    qv.z = q4(f2.x * inv, f2.y * inv, f2.z * inv, f2.w * inv);
    qv.w = q4(f3.x * inv, f3.y * inv, f3.z * inv, f3.w * inv);
    dst[u] = qv;
  }
}

// ---------- per-pair activation quant ----------
__global__ __launch_bounds__(256) void quantx_k(const float* __restrict__ x,
                                                const int* __restrict__ pair_tok,
                                                const int* __restrict__ offs,
                                                const float* __restrict__ s13,
                                                unsigned char* __restrict__ Xq) {
  int p = blockIdx.x;
  int t = pair_tok[p];
  int e = 0;
#pragma unroll
  for (int j = 1; j < E_NUM; j++) { if (p >= offs[j]) e = j; }
  float inv = 1.f / s13[e];
  float4 v = ((const float4*)(x + (size_t)t * H_DIM))[threadIdx.x];
  float a = fminf(448.f, fmaxf(-448.f, v.x * inv));
  float b = fminf(448.f, fmaxf(-448.f, v.y * inv));
  float c = fminf(448.f, fmaxf(-448.f, v.z * inv));
  float d = fminf(448.f, fmaxf(-448.f, v.w * inv));
  ((unsigned*)(Xq + (size_t)p * H_DIM))[threadIdx.x] = q4(a, b, c, d);
}

// ---------- GEMM1: BM=64, per-wave 16 rows, fused silu*mul + act quant ----------
template <bool PREQ>
__global__ __launch_bounds__(256) void gemm1_k(const unsigned char* __restrict__ Wq13,
                                               const float* __restrict__ w13f,
                                               const unsigned char* __restrict__ Xq,
                                               unsigned char* __restrict__ H1,
                                               const int* __restrict__ cnt,
                                               const int* __restrict__ offs,
                                               const unsigned* __restrict__ amax13,
                                               const float* __restrict__ s13,
                                               const float* __restrict__ s2in) {
  const int e = blockIdx.z;
  const int count = cnt[e];
  const int m0 = blockIdx.y * 64;
  if (m0 >= count) return;
  const int nt = blockIdx.x;
  const int base = offs[e];

  const float amax = __uint_as_float(amax13[e]);
  const float inv_w = 448.f / amax;
  const float gs = s13[e] * (amax / 448.f);
  const float inv_a2 = 1.f / s2in[e];

  __shared__ __align__(16) unsigned char As[64][80];
  __shared__ __align__(16) unsigned char Bg[64][80];
  __shared__ __align__(16) unsigned char Bu[64][80];

  const int tid = threadIdx.x, lane = tid & 63, wq = tid >> 6;
  const int fr = lane & 15, ks = lane >> 4;

  f32x4 accg[4], accu[4];
#pragma unroll
  for (int i = 0; i < 4; i++) { accg[i] = (f32x4)0.f; accu[i] = (f32x4)0.f; }

  const int row = tid >> 2, seg = tid & 3;
  int pr = base + m0 + row; if (pr > PAIRS - 1) pr = PAIRS - 1;
  const unsigned char* a_src = Xq + (size_t)pr * H_DIM + seg * 16;
  const size_t gbase = ((size_t)e * 2 * I_DIM + (size_t)nt * 64 + row) * H_DIM + seg * 16;
  const size_t ubase = gbase + (size_t)I_DIM * H_DIM;

  u32x4 ra, rgv, ruv;
  auto loadq = [&](const float* p) {
    float4 f0 = ((const float4*)p)[0], f1 = ((const float4*)p)[1];
    float4 f2 = ((const float4*)p)[2], f3 = ((const float4*)p)[3];
    u32x4 qv;
    qv.x = q4(f0.x * inv_w, f0.y * inv_w, f0.z * inv_w, f0.w * inv_w);
    qv.y = q4(f1.x * inv_w, f1.y * inv_w, f1.z * inv_w, f1.w * inv_w);
    qv.z = q4(f2.x * inv_w, f2.y * inv_w, f2.z * inv_w, f2.w * inv_w);
    qv.w = q4(f3.x * inv_w, f3.y * inv_w, f3.z * inv_w, f3.w * inv_w);
    return qv;
  };

  ra = *(const u32x4*)a_src;
  if constexpr (PREQ) {
    rgv = *(const u32x4*)(Wq13 + gbase);
    ruv = *(const u32x4*)(Wq13 + ubase);
  } else {
    rgv = loadq(w13f + gbase);
    ruv = loadq(w13f + ubase);
  }

  for (int t = 0; t < H_DIM / 64; ++t) {
    __syncthreads();
    *(u32x4*)&As[row][seg * 16] = ra;
    *(u32x4*)&Bg[row][seg * 16] = rgv;
    *(u32x4*)&Bu[row][seg * 16] = ruv;
    __syncthreads();
    if (t + 1 < H_DIM / 64) {
      int k0 = (t + 1) * 64;
      ra = *(const u32x4*)(a_src + k0);
      if constexpr (PREQ) {
        rgv = *(const u32x4*)(Wq13 + gbase + k0);
        ruv = *(const u32x4*)(Wq13 + ubase + k0);
      } else {
        rgv = loadq(w13f + gbase + k0);
        ruv = loadq(w13f + ubase + k0);
      }
    }
    i64 a0 = *(const i64*)&As[wq * 16 + fr][ks * 8];
    i64 a1 = *(const i64*)&As[wq * 16 + fr][32 + ks * 8];
#pragma unroll
    for (int ni = 0; ni < 4; ni++) {
      i64 b0 = *(const i64*)&Bg[ni * 16 + fr][ks * 8];
      i64 b1 = *(const i64*)&Bg[ni * 16 + fr][32 + ks * 8];
      accg[ni] = __builtin_amdgcn_mfma_f32_16x16x32_fp8_fp8(a0, b0, accg[ni], 0, 0, 0);
      accg[ni] = __builtin_amdgcn_mfma_f32_16x16x32_fp8_fp8(a1, b1, accg[ni], 0, 0, 0);
      i64 c0 = *(const i64*)&Bu[ni * 16 + fr][ks * 8];
      i64 c1 = *(const i64*)&Bu[ni * 16 + fr][32 + ks * 8];
      accu[ni] = __builtin_amdgcn_mfma_f32_16x16x32_fp8_fp8(a0, c0, accu[ni], 0, 0, 0);
      accu[ni] = __builtin_amdgcn_mfma_f32_16x16x32_fp8_fp8(a1, c1, accu[ni], 0, 0, 0);
    }
  }

  const int rg = lane >> 4;
#pragma unroll
  for (int rr = 0; rr < 4; rr++) {
    int lrow = wq * 16 + rg * 4 + rr;
    if (m0 + lrow < count) {
      size_t p = (size_t)(base + m0 + lrow);
#pragma unroll
      for (int ni = 0; ni < 4; ni++) {
        int col = nt * 64 + ni * 16 + fr;
        float g = accg[ni][rr] * gs;
        float u = accu[ni][rr] * gs;
        float act = g / (1.f + expf(-g)) * u * inv_a2;
        act = fminf(448.f, fmaxf(-448.f, act));
        H1[p * I_DIM + col] = q1(act);
      }
    }
  }
}

// ---------- GEMM2: BM=64, BN=64 ----------
template <bool PREQ, bool ATOMIC>
__global__ __launch_bounds__(256) void gemm2_k(const unsigned char* __restrict__ Wq2,
                                               const float* __restrict__ w2f,
                                               const unsigned char* __restrict__ H1,
                                               float* __restrict__ O,
                                               float* __restrict__ out,
                                               const int* __restrict__ cnt,
                                               const int* __restrict__ offs,
                                               const unsigned* __restrict__ amax2,
                                               const float* __restrict__ s2in,
                                               const int* __restrict__ pair_tok,
                                               const float* __restrict__ pair_w) {
  const int e = blockIdx.z;
  const int count = cnt[e];
  const int m0 = blockIdx.y * 64;
  if (m0 >= count) return;
  const int n0 = blockIdx.x * 64;
  const int base = offs[e];

  const float amax = __uint_as_float(amax2[e]);
  const float inv_w = 448.f / amax;
  const float s2 = s2in[e] * (amax / 448.f);

  __shared__ __align__(16) unsigned char As[64][80];
  __shared__ __align__(16) unsigned char Bs[64][80];

  const int tid = threadIdx.x, lane = tid & 63, wq = tid >> 6;
  const int fr = lane & 15, ks = lane >> 4;

  f32x4 acc[4];
#pragma unroll
  for (int i = 0; i < 4; i++) acc[i] = (f32x4)0.f;

  const int row = tid >> 2, seg = tid & 3;
  int pr = base + m0 + row; if (pr > PAIRS - 1) pr = PAIRS - 1;
  const unsigned char* a_src = H1 + (size_t)pr * I_DIM + seg * 16;
  const size_t bbase = ((size_t)e * H_DIM + n0 + row) * I_DIM + seg * 16;

  u32x4 ra, rb;
  auto loadq = [&](const float* p) {
    float4 f0 = ((const float4*)p)[0], f1 = ((const float4*)p)[1];
    float4 f2 = ((const float4*)p)[2], f3 = ((const float4*)p)[3];
    u32x4 qv;
    qv.x = q4(f0.x * inv_w, f0.y * inv_w, f0.z * inv_w, f0.w * inv_w);
    qv.y = q4(f1.x * inv_w, f1.y * inv_w, f1.z * inv_w, f1.w * inv_w);
    qv.z = q4(f2.x * inv_w, f2.y * inv_w, f2.z * inv_w, f2.w * inv_w);
    qv.w = q4(f3.x * inv_w, f3.y * inv_w, f3.z * inv_w, f3.w * inv_w);
    return qv;
  };

  ra = *(const u32x4*)a_src;
  if constexpr (PREQ) rb = *(const u32x4*)(Wq2 + bbase);
  else rb = loadq(w2f + bbase);

  for (int t = 0; t < I_DIM / 64; ++t) {
    __syncthreads();
    *(u32x4*)&As[row][seg * 16] = ra;
    *(u32x4*)&Bs[row][seg * 16] = rb;
    __syncthreads();
    if (t + 1 < I_DIM / 64) {
      int k0 = (t + 1) * 64;
      ra = *(const u32x4*)(a_src + k0);
      if constexpr (PREQ) rb = *(const u32x4*)(Wq2 + bbase + k0);
      else rb = loadq(w2f + bbase + k0);
    }
    i64 a0 = *(const i64*)&As[wq * 16 + fr][ks * 8];
    i64 a1 = *(const i64*)&As[wq * 16 + fr][32 + ks * 8];
#pragma unroll
    for (int ni = 0; ni < 4; ni++) {
      i64 b0 = *(const i64*)&Bs[ni * 16 + fr][ks * 8];
      i64 b1 = *(const i64*)&Bs[ni * 16 + fr][32 + ks * 8];
      acc[ni] = __builtin_amdgcn_mfma_f32_16x16x32_fp8_fp8(a0, b0, acc[ni], 0, 0, 0);
      acc[ni] = __builtin_amdgcn_mfma_f32_16x16x32_fp8_fp8(a1, b1, acc[ni], 0, 0, 0);
    }
  }

  const int rg = lane >> 4;
#pragma unroll
  for (int rr = 0; rr < 4; rr++) {
    int lrow = wq * 16 + rg * 4 + rr;
    if (m0 + lrow < count) {
      size_t p = (size_t)(base + m0 + lrow);
      int tt = pair_tok[p];
      float pw = pair_w[p];
#pragma unroll
      for (int ni = 0; ni < 4; ni++) {
        int col = n0 + ni * 16 + fr;
        float val = acc[ni][rr] * s2 * pw;
        if (ATOMIC) atomicAdd(&out[(size_t)tt * H_DIM + col], val);
        else O[p * H_DIM + col] = val;
      }
    }
  }
}

// ---------- combine ----------
__global__ __launch_bounds__(256) void combine_k(const float* __restrict__ O,
                                                 const int* __restrict__ pairidx,
                                                 float* __restrict__ out) {
  int t = blockIdx.x;
  int p0 = pairidx[2 * t], p1 = pairidx[2 * t + 1];
  float4 a = ((const float4*)(O + (size_t)p0 * H_DIM))[threadIdx.x];
  float4 b = ((const float4*)(O + (size_t)p1 * H_DIM))[threadIdx.x];
  float4 r;
  r.x = a.x + b.x; r.y = a.y + b.y; r.z = a.z + b.z; r.w = a.w + b.w;
  ((float4*)(out + (size_t)t * H_DIM))[threadIdx.x] = r;
}

extern "C" void kernel_launch(void* const* d_in, const int* in_sizes, int n_in,
                              void* d_out, int out_size, void* d_ws, size_t ws_size,
                              hipStream_t stream) {
  (void)in_sizes; (void)n_in; (void)out_size;
  const float* x      = (const float*)d_in[0];
  const float* logits = (const float*)d_in[1];
  const float* w13    = (const float*)d_in[2];
  const float* w2     = (const float*)d_in[3];
  const float* s13    = (const float*)d_in[4];
  const float* s2in   = (const float*)d_in[5];
  float* out = (float*)d_out;

  char* ws = (char*)d_ws;
  unsigned* amax13 = (unsigned*)(ws + 0);
  unsigned* amax2  = (unsigned*)(ws + 64);
  int* cnt     = (int*)(ws + 128);
  int* offs    = (int*)(ws + 192);
  int* tk_id   = (int*)(ws + 1024);
  float* tk_w  = (float*)(ws + 9216);
  int* pair_tok = (int*)(ws + 17408);
  float* pair_w = (float*)(ws + 25600);
  int* pairidx  = (int*)(ws + 33792);
  unsigned char* Xq = (unsigned char*)(ws + (size_t)(1 << 20));        // 2 MB
  unsigned char* H1 = (unsigned char*)(ws + (size_t)4 * (1 << 20));    // 5.77 MB
  float* O          = (float*)(ws + (size_t)10 * (1 << 20));           // 8 MB
  unsigned char* Wq13 = (unsigned char*)(ws + (size_t)18 * (1 << 20)); // 46.14 MB
  unsigned char* Wq2  = Wq13 + (size_t)E_NUM * 2 * I_DIM * H_DIM;      // 23.07 MB

  size_t need_O = (size_t)10 * (1 << 20) + (size_t)PAIRS * H_DIM * 4;
  size_t need_preq = ((size_t)18 * (1 << 20)) + (size_t)E_NUM * 2 * I_DIM * H_DIM
                   + (size_t)E_NUM * H_DIM * I_DIM;
  bool preq = ws_size >= need_preq;
  bool useO = ws_size >= need_O;

  init_k<<<4, 256, 0, stream>>>((unsigned*)ws);

  routing_k<<<T_TOK / 256, 256, 0, stream>>>(logits, tk_id, tk_w, cnt);
  offsets_k<<<1, 64, 0, stream>>>(cnt, offs);
  scatter_k<<<E_NUM, 256, 0, stream>>>(tk_id, tk_w, offs, pair_tok, pair_w, pairidx);

  amax_k<<<dim3(64, E_NUM), 256, 0, stream>>>(w13, amax13, 2 * I_DIM * H_DIM / 4, 88);
  amax_k<<<dim3(64, E_NUM), 256, 0, stream>>>(w2, amax2, H_DIM * I_DIM / 4, 44);

  if (preq) {
    quantw_k<<<dim3(128, E_NUM), 256, 0, stream>>>(w13, Wq13, amax13, 2 * I_DIM * H_DIM / 16, 11);
    quantw_k<<<dim3(64, E_NUM), 256, 0, stream>>>(w2, Wq2, amax2, H_DIM * I_DIM / 16, 11);
  }

  quantx_k<<<PAIRS, 256, 0, stream>>>(x, pair_tok, offs, s13, Xq);

  if (preq) {
    gemm1_k<true><<<dim3(I_DIM / 64, 32, E_NUM), 256, 0, stream>>>(
        Wq13, w13, Xq, H1, cnt, offs, amax13, s13, s2in);
  } else {
    gemm1_k<false><<<dim3(I_DIM / 64, 32, E_NUM), 256, 0, stream>>>(
        Wq13, w13, Xq, H1, cnt, offs, amax13, s13, s2in);
  }

  if (useO) {
    if (preq) {
      gemm2_k<true, false><<<dim3(H_DIM / 64, 32, E_NUM), 256, 0, stream>>>(
          Wq2, w2, H1, O, out, cnt, offs, amax2, s2in, pair_tok, pair_w);
    } else {
      gemm2_k<false, false><<<dim3(H_DIM / 64, 32, E_NUM), 256, 0, stream>>>(
          Wq2, w2, H1, O, out, cnt, offs, amax2, s2in, pair_tok, pair_w);
    }
    combine_k<<<T_TOK, 256, 0, stream>>>(O, pairidx, out);
  } else {
    hipMemsetAsync(out, 0, (size_t)T_TOK * H_DIM * 4, stream);
    gemm2_k<false, true><<<dim3(H_DIM / 64, 32, E_NUM), 256, 0, stream>>>(
        Wq2, w2, H1, out, out, cnt, offs, amax2, s2in, pair_tok, pair_w);
  }
}

// Round 4
// 248.457 us; speedup vs baseline: 1.8477x; 1.0146x over previous
//
#include <hip/hip_runtime.h>
#include <cstdint>
#include <cstddef>

#define T_TOK 1024
#define H_DIM 1024
#define I_DIM 2816
#define E_NUM 8
#define PAIRS 2048  // T_TOK * top_k(=2)

typedef __attribute__((ext_vector_type(4))) float f32x4;
typedef __attribute__((ext_vector_type(4))) unsigned int u32x4;
typedef long i64;

// ---------- fp8 e4m3fn encode ----------
__device__ __forceinline__ unsigned char fp8e4m3_sw(float v) {
  v = fminf(448.f, fmaxf(-448.f, v));
  unsigned b = __float_as_uint(v);
  unsigned s = (b >> 24) & 0x80u;
  float a = fabsf(v);
  if (a < 0.015625f) {
    int m = (int)rintf(a * 512.f);
    return (unsigned char)(s | (unsigned)m);
  }
  unsigned ab = b & 0x7fffffffu;
  unsigned rnd = 0x7FFFFu + ((ab >> 20) & 1u);
  ab += rnd;
  int e = (int)(ab >> 23) - 127;
  unsigned m = (ab >> 20) & 7u;
  if (e > 8 || (e == 8 && m > 6)) { e = 8; m = 6; }
  return (unsigned char)(s | (unsigned)((e + 7) << 3) | m);
}

__device__ __forceinline__ unsigned q4(float a, float b, float c, float d) {
#if __has_builtin(__builtin_amdgcn_cvt_pk_fp8_f32)
  unsigned w = (unsigned)__builtin_amdgcn_cvt_pk_fp8_f32(a, b, 0, false);
  return (unsigned)__builtin_amdgcn_cvt_pk_fp8_f32(c, d, (int)w, true);
#else
  return (unsigned)fp8e4m3_sw(a) | ((unsigned)fp8e4m3_sw(b) << 8) |
         ((unsigned)fp8e4m3_sw(c) << 16) | ((unsigned)fp8e4m3_sw(d) << 24);
#endif
}

__device__ __forceinline__ unsigned char q1(float a) {
#if __has_builtin(__builtin_amdgcn_cvt_pk_fp8_f32)
  return (unsigned char)((unsigned)__builtin_amdgcn_cvt_pk_fp8_f32(a, a, 0, false) & 0xFFu);
#else
  return fp8e4m3_sw(a);
#endif
}

// quantize 16 consecutive f32 (4 float4) to 16 fp8 bytes
__device__ __forceinline__ u32x4 q16(const float* p, float inv) {
  float4 f0 = ((const float4*)p)[0], f1 = ((const float4*)p)[1];
  float4 f2 = ((const float4*)p)[2], f3 = ((const float4*)p)[3];
  u32x4 qv;
  qv.x = q4(f0.x * inv, f0.y * inv, f0.z * inv, f0.w * inv);
  qv.y = q4(f1.x * inv, f1.y * inv, f1.z * inv, f1.w * inv);
  qv.z = q4(f2.x * inv, f2.y * inv, f2.z * inv, f2.w * inv);
  qv.w = q4(f3.x * inv, f3.y * inv, f3.z * inv, f3.w * inv);
  return qv;
}

// ---------- init: zero control region ----------
__global__ void init_k(unsigned* __restrict__ p) {
  p[blockIdx.x * 256 + threadIdx.x] = 0;
}

// ---------- routing ----------
__global__ __launch_bounds__(256) void routing_k(const float* __restrict__ logits,
                                                 int* __restrict__ tk_id,
                                                 float* __restrict__ tk_w,
                                                 int* __restrict__ cnt) {
  int t = blockIdx.x * 256 + threadIdx.x;
  if (t >= T_TOK) return;
  float l[E_NUM];
#pragma unroll
  for (int j = 0; j < E_NUM; j++) l[j] = logits[t * E_NUM + j];
  int i0 = 0; float b0 = l[0];
#pragma unroll
  for (int j = 1; j < E_NUM; j++) { if (l[j] > b0) { b0 = l[j]; i0 = j; } }
  int i1 = -1; float b1 = -3.4e38f;
#pragma unroll
  for (int j = 0; j < E_NUM; j++) { if (j != i0 && l[j] > b1) { b1 = l[j]; i1 = j; } }
  float e1 = expf(b1 - b0);
  float d = 1.f + e1;
  tk_id[2 * t] = i0; tk_id[2 * t + 1] = i1;
  tk_w[2 * t] = 1.f / d; tk_w[2 * t + 1] = e1 / d;
  atomicAdd(&cnt[i0], 1);
  atomicAdd(&cnt[i1], 1);
}

__global__ void offsets_k(const int* __restrict__ cnt, int* __restrict__ offs) {
  if (threadIdx.x == 0 && blockIdx.x == 0) {
    int s = 0;
#pragma unroll
    for (int e = 0; e < E_NUM; e++) { offs[e] = s; s += cnt[e]; }
    offs[E_NUM] = s;
  }
}

__global__ __launch_bounds__(256) void scatter_k(const int* __restrict__ tk_id,
                                                 const float* __restrict__ tk_w,
                                                 const int* __restrict__ offs,
                                                 int* __restrict__ pair_tok,
                                                 float* __restrict__ pair_w,
                                                 int* __restrict__ pairidx) {
  int e = blockIdx.x;
  int tid = threadIdx.x, lane = tid & 63, wid = tid >> 6;
  __shared__ int wsum[4];
  int run = offs[e];
  for (int c = 0; c < T_TOK; c += 256) {
    int t = c + tid;
    int sel = -1;
    if (tk_id[2 * t] == e) sel = 0;
    else if (tk_id[2 * t + 1] == e) sel = 1;
    unsigned long long m = __ballot(sel >= 0);
    int rank = __popcll(m & ((1ull << lane) - 1ull));
    if (lane == 0) wsum[wid] = __popcll(m);
    __syncthreads();
    int wbase = 0;
#pragma unroll
    for (int j = 0; j < 4; j++) { if (j < wid) wbase += wsum[j]; }
    if (sel >= 0) {
      int p = run + wbase + rank;
      pair_tok[p] = t;
      pair_w[p] = tk_w[2 * t + sel];
      pairidx[2 * t + sel] = p;
    }
    run += wsum[0] + wsum[1] + wsum[2] + wsum[3];
    __syncthreads();
  }
}

// ---------- per-expert amax (grid-stride, 1 atomic per block) ----------
__global__ __launch_bounds__(256) void amax_k(const float* __restrict__ w,
                                              unsigned* __restrict__ amax_bits,
                                              int nf4_per_e, int iters) {
  int e = blockIdx.y;
  const float4* src = (const float4*)w + (size_t)e * nf4_per_e;
  int idx = blockIdx.x * 256 + threadIdx.x;
  int stride = gridDim.x * 256;
  float m = 0.f;
  for (int j = 0; j < iters; j += 4) {
    float4 v0 = src[idx + (size_t)(j + 0) * stride];
    float4 v1 = src[idx + (size_t)(j + 1) * stride];
    float4 v2 = src[idx + (size_t)(j + 2) * stride];
    float4 v3 = src[idx + (size_t)(j + 3) * stride];
    m = fmaxf(m, fmaxf(fmaxf(fabsf(v0.x), fabsf(v0.y)), fmaxf(fabsf(v0.z), fabsf(v0.w))));
    m = fmaxf(m, fmaxf(fmaxf(fabsf(v1.x), fabsf(v1.y)), fmaxf(fabsf(v1.z), fabsf(v1.w))));
    m = fmaxf(m, fmaxf(fmaxf(fabsf(v2.x), fabsf(v2.y)), fmaxf(fabsf(v2.z), fabsf(v2.w))));
    m = fmaxf(m, fmaxf(fmaxf(fabsf(v3.x), fabsf(v3.y)), fmaxf(fabsf(v3.z), fabsf(v3.w))));
  }
#pragma unroll
  for (int off = 32; off > 0; off >>= 1) m = fmaxf(m, __shfl_xor(m, off));
  __shared__ float wmax[4];
  int lane = threadIdx.x & 63, wid = threadIdx.x >> 6;
  if (lane == 0) wmax[wid] = m;
  __syncthreads();
  if (threadIdx.x == 0) {
    float mm = fmaxf(fmaxf(wmax[0], wmax[1]), fmaxf(wmax[2], wmax[3]));
    atomicMax(&amax_bits[e], __float_as_uint(mm));
  }
}

// ---------- per-pair activation quant ----------
__global__ __launch_bounds__(256) void quantx_k(const float* __restrict__ x,
                                                const int* __restrict__ pair_tok,
                                                const int* __restrict__ offs,
                                                const float* __restrict__ s13,
                                                unsigned char* __restrict__ Xq) {
  int p = blockIdx.x;
  int t = pair_tok[p];
  int e = 0;
#pragma unroll
  for (int j = 1; j < E_NUM; j++) { if (p >= offs[j]) e = j; }
  float inv = 1.f / s13[e];
  float4 v = ((const float4*)(x + (size_t)t * H_DIM))[threadIdx.x];
  float a = fminf(448.f, fmaxf(-448.f, v.x * inv));
  float b = fminf(448.f, fmaxf(-448.f, v.y * inv));
  float c = fminf(448.f, fmaxf(-448.f, v.z * inv));
  float d = fminf(448.f, fmaxf(-448.f, v.w * inv));
  ((unsigned*)(Xq + (size_t)p * H_DIM))[threadIdx.x] = q4(a, b, c, d);
}

// ---------- GEMM1: BM=256, BN=64(gate)+64(up), BK=64, 512 threads (8 waves) ----------
// weights read from HBM exactly once (inline f32->fp8 quant in staging)
__global__ __launch_bounds__(512) void gemm1_k(const float* __restrict__ w13,
                                               const unsigned char* __restrict__ Xq,
                                               unsigned char* __restrict__ H1,
                                               const int* __restrict__ cnt,
                                               const int* __restrict__ offs,
                                               const unsigned* __restrict__ amax13,
                                               const float* __restrict__ s13,
                                               const float* __restrict__ s2in) {
  const int e = blockIdx.z;
  const int count = cnt[e];
  const int m0 = blockIdx.y * 256;
  if (m0 >= count) return;
  const int nt = blockIdx.x;
  const int base = offs[e];

  const float amax = __uint_as_float(amax13[e]);
  const float inv_w = 448.f / amax;
  const float gs = s13[e] * (amax / 448.f);
  const float inv_a2 = 1.f / s2in[e];

  __shared__ __align__(16) unsigned char As[256][80];
  __shared__ __align__(16) unsigned char Bs[128][80];  // rows 0..63 gate, 64..127 up

  const int tid = threadIdx.x, lane = tid & 63, wq = tid >> 6;
  const int fr = lane & 15, ks = lane >> 4;

  f32x4 accg[2][4], accu[2][4];
#pragma unroll
  for (int i = 0; i < 2; i++)
#pragma unroll
    for (int j = 0; j < 4; j++) { accg[i][j] = (f32x4)0.f; accu[i][j] = (f32x4)0.f; }

  // A staging: 1024 slots (256 rows x 4 segs of 16B); this thread: tid, tid+512
  const int ar0 = tid >> 2, ar1 = (tid + 512) >> 2, aseg = tid & 3;
  int pr0 = base + m0 + ar0; if (pr0 > PAIRS - 1) pr0 = PAIRS - 1;
  int pr1 = base + m0 + ar1; if (pr1 > PAIRS - 1) pr1 = PAIRS - 1;
  const unsigned char* a_src0 = Xq + (size_t)pr0 * H_DIM + aseg * 16;
  const unsigned char* a_src1 = Xq + (size_t)pr1 * H_DIM + aseg * 16;

  // B staging: 512 slots (128 rows x 4 segs of 16 f32 -> 16B fp8)
  const int brow = tid >> 2, bseg = tid & 3;
  const float* b_src = w13 + ((size_t)e * 2 * I_DIM + (size_t)nt * 64 +
                              (brow & 63) + (size_t)(brow >> 6) * I_DIM) * H_DIM + bseg * 16;

  u32x4 ra0 = *(const u32x4*)a_src0;
  u32x4 ra1 = *(const u32x4*)a_src1;
  u32x4 rb = q16(b_src, inv_w);

  for (int t = 0; t < H_DIM / 64; ++t) {
    __syncthreads();
    *(u32x4*)&As[ar0][aseg * 16] = ra0;
    *(u32x4*)&As[ar1][aseg * 16] = ra1;
    *(u32x4*)&Bs[brow][bseg * 16] = rb;
    __syncthreads();
    if (t + 1 < H_DIM / 64) {
      int k0 = (t + 1) * 64;
      ra0 = *(const u32x4*)(a_src0 + k0);
      ra1 = *(const u32x4*)(a_src1 + k0);
      rb = q16(b_src + k0, inv_w);
    }
#pragma unroll
    for (int kk = 0; kk < 2; kk++) {
      i64 a0 = *(const i64*)&As[wq * 32 + fr][kk * 32 + ks * 8];
      i64 a1 = *(const i64*)&As[wq * 32 + 16 + fr][kk * 32 + ks * 8];
#pragma unroll
      for (int ni = 0; ni < 4; ni++) {
        i64 bg = *(const i64*)&Bs[ni * 16 + fr][kk * 32 + ks * 8];
        i64 bu = *(const i64*)&Bs[64 + ni * 16 + fr][kk * 32 + ks * 8];
        accg[0][ni] = __builtin_amdgcn_mfma_f32_16x16x32_fp8_fp8(a0, bg, accg[0][ni], 0, 0, 0);
        accg[1][ni] = __builtin_amdgcn_mfma_f32_16x16x32_fp8_fp8(a1, bg, accg[1][ni], 0, 0, 0);
        accu[0][ni] = __builtin_amdgcn_mfma_f32_16x16x32_fp8_fp8(a0, bu, accu[0][ni], 0, 0, 0);
        accu[1][ni] = __builtin_amdgcn_mfma_f32_16x16x32_fp8_fp8(a1, bu, accu[1][ni], 0, 0, 0);
      }
    }
  }

  const int rg = lane >> 4;
#pragma unroll
  for (int mi = 0; mi < 2; mi++) {
#pragma unroll
    for (int rr = 0; rr < 4; rr++) {
      int lrow = wq * 32 + mi * 16 + rg * 4 + rr;
      if (m0 + lrow < count) {
        size_t p = (size_t)(base + m0 + lrow);
#pragma unroll
        for (int ni = 0; ni < 4; ni++) {
          int col = nt * 64 + ni * 16 + fr;
          float g = accg[mi][ni][rr] * gs;
          float u = accu[mi][ni][rr] * gs;
          float act = g / (1.f + expf(-g)) * u * inv_a2;
          act = fminf(448.f, fmaxf(-448.f, act));
          H1[p * I_DIM + col] = q1(act);
        }
      }
    }
  }
}

// ---------- GEMM2: BM=256, BN=64, BK=64, 512 threads ----------
template <bool ATOMIC>
__global__ __launch_bounds__(512) void gemm2_k(const float* __restrict__ w2,
                                               const unsigned char* __restrict__ H1,
                                               float* __restrict__ O,
                                               float* __restrict__ out,
                                               const int* __restrict__ cnt,
                                               const int* __restrict__ offs,
                                               const unsigned* __restrict__ amax2,
                                               const float* __restrict__ s2in,
                                               const int* __restrict__ pair_tok,
                                               const float* __restrict__ pair_w) {
  const int e = blockIdx.z;
  const int count = cnt[e];
  const int m0 = blockIdx.y * 256;
  if (m0 >= count) return;
  const int n0 = blockIdx.x * 64;
  const int base = offs[e];

  const float amax = __uint_as_float(amax2[e]);
  const float inv_w = 448.f / amax;
  const float s2 = s2in[e] * (amax / 448.f);

  __shared__ __align__(16) unsigned char As[256][80];
  __shared__ __align__(16) unsigned char Bs[64][80];

  const int tid = threadIdx.x, lane = tid & 63, wq = tid >> 6;
  const int fr = lane & 15, ks = lane >> 4;

  f32x4 acc[2][4];
#pragma unroll
  for (int i = 0; i < 2; i++)
#pragma unroll
    for (int j = 0; j < 4; j++) acc[i][j] = (f32x4)0.f;

  const int ar0 = tid >> 2, ar1 = (tid + 512) >> 2, aseg = tid & 3;
  int pr0 = base + m0 + ar0; if (pr0 > PAIRS - 1) pr0 = PAIRS - 1;
  int pr1 = base + m0 + ar1; if (pr1 > PAIRS - 1) pr1 = PAIRS - 1;
  const unsigned char* a_src0 = H1 + (size_t)pr0 * I_DIM + aseg * 16;
  const unsigned char* a_src1 = H1 + (size_t)pr1 * I_DIM + aseg * 16;

  // B: 64 rows x 4 segs = 256 slots, staged by tid < 256
  const int brow = (tid & 255) >> 2, bseg = tid & 3;
  const float* b_src = w2 + ((size_t)e * H_DIM + n0 + brow) * I_DIM + bseg * 16;

  u32x4 ra0 = *(const u32x4*)a_src0;
  u32x4 ra1 = *(const u32x4*)a_src1;
  u32x4 rb;
  if (tid < 256) rb = q16(b_src, inv_w);

  for (int t = 0; t < I_DIM / 64; ++t) {
    __syncthreads();
    *(u32x4*)&As[ar0][aseg * 16] = ra0;
    *(u32x4*)&As[ar1][aseg * 16] = ra1;
    if (tid < 256) *(u32x4*)&Bs[brow][bseg * 16] = rb;
    __syncthreads();
    if (t + 1 < I_DIM / 64) {
      int k0 = (t + 1) * 64;
      ra0 = *(const u32x4*)(a_src0 + k0);
      ra1 = *(const u32x4*)(a_src1 + k0);
      if (tid < 256) rb = q16(b_src + k0, inv_w);
    }
#pragma unroll
    for (int kk = 0; kk < 2; kk++) {
      i64 a0 = *(const i64*)&As[wq * 32 + fr][kk * 32 + ks * 8];
      i64 a1 = *(const i64*)&As[wq * 32 + 16 + fr][kk * 32 + ks * 8];
#pragma unroll
      for (int ni = 0; ni < 4; ni++) {
        i64 b = *(const i64*)&Bs[ni * 16 + fr][kk * 32 + ks * 8];
        acc[0][ni] = __builtin_amdgcn_mfma_f32_16x16x32_fp8_fp8(a0, b, acc[0][ni], 0, 0, 0);
        acc[1][ni] = __builtin_amdgcn_mfma_f32_16x16x32_fp8_fp8(a1, b, acc[1][ni], 0, 0, 0);
      }
    }
  }

  const int rg = lane >> 4;
#pragma unroll
  for (int mi = 0; mi < 2; mi++) {
#pragma unroll
    for (int rr = 0; rr < 4; rr++) {
      int lrow = wq * 32 + mi * 16 + rg * 4 + rr;
      if (m0 + lrow < count) {
        size_t p = (size_t)(base + m0 + lrow);
        int tt = pair_tok[p];
        float pw = pair_w[p];
#pragma unroll
        for (int ni = 0; ni < 4; ni++) {
          int col = n0 + ni * 16 + fr;
          float val = acc[mi][ni][rr] * s2 * pw;
          if (ATOMIC) atomicAdd(&out[(size_t)tt * H_DIM + col], val);
          else O[p * H_DIM + col] = val;
        }
      }
    }
  }
}

// ---------- combine ----------
__global__ __launch_bounds__(256) void combine_k(const float* __restrict__ O,
                                                 const int* __restrict__ pairidx,
                                                 float* __restrict__ out) {
  int t = blockIdx.x;
  int p0 = pairidx[2 * t], p1 = pairidx[2 * t + 1];
  float4 a = ((const float4*)(O + (size_t)p0 * H_DIM))[threadIdx.x];
  float4 b = ((const float4*)(O + (size_t)p1 * H_DIM))[threadIdx.x];
  float4 r;
  r.x = a.x + b.x; r.y = a.y + b.y; r.z = a.z + b.z; r.w = a.w + b.w;
  ((float4*)(out + (size_t)t * H_DIM))[threadIdx.x] = r;
}

extern "C" void kernel_launch(void* const* d_in, const int* in_sizes, int n_in,
                              void* d_out, int out_size, void* d_ws, size_t ws_size,
                              hipStream_t stream) {
  (void)in_sizes; (void)n_in; (void)out_size;
  const float* x      = (const float*)d_in[0];
  const float* logits = (const float*)d_in[1];
  const float* w13    = (const float*)d_in[2];
  const float* w2     = (const float*)d_in[3];
  const float* s13    = (const float*)d_in[4];
  const float* s2in   = (const float*)d_in[5];
  float* out = (float*)d_out;

  char* ws = (char*)d_ws;
  unsigned* amax13 = (unsigned*)(ws + 0);
  unsigned* amax2  = (unsigned*)(ws + 64);
  int* cnt     = (int*)(ws + 128);
  int* offs    = (int*)(ws + 192);
  int* tk_id   = (int*)(ws + 1024);
  float* tk_w  = (float*)(ws + 9216);
  int* pair_tok = (int*)(ws + 17408);
  float* pair_w = (float*)(ws + 25600);
  int* pairidx  = (int*)(ws + 33792);
  unsigned char* Xq = (unsigned char*)(ws + (size_t)(1 << 20));        // 2 MB
  unsigned char* H1 = (unsigned char*)(ws + (size_t)4 * (1 << 20));    // 5.77 MB
  float* O          = (float*)(ws + (size_t)10 * (1 << 20));           // 8 MB

  init_k<<<4, 256, 0, stream>>>((unsigned*)ws);

  routing_k<<<T_TOK / 256, 256, 0, stream>>>(logits, tk_id, tk_w, cnt);
  offsets_k<<<1, 64, 0, stream>>>(cnt, offs);
  scatter_k<<<E_NUM, 256, 0, stream>>>(tk_id, tk_w, offs, pair_tok, pair_w, pairidx);

  amax_k<<<dim3(128, E_NUM), 256, 0, stream>>>(w13, amax13, 2 * I_DIM * H_DIM / 4, 44);
  amax_k<<<dim3(64, E_NUM), 256, 0, stream>>>(w2, amax2, H_DIM * I_DIM / 4, 44);

  quantx_k<<<PAIRS, 256, 0, stream>>>(x, pair_tok, offs, s13, Xq);

  gemm1_k<<<dim3(I_DIM / 64, 4, E_NUM), 512, 0, stream>>>(
      w13, Xq, H1, cnt, offs, amax13, s13, s2in);

  size_t need_O = (size_t)10 * (1 << 20) + (size_t)PAIRS * H_DIM * 4;
  if (ws_size >= need_O) {
    gemm2_k<false><<<dim3(H_DIM / 64, 4, E_NUM), 512, 0, stream>>>(
        w2, H1, O, out, cnt, offs, amax2, s2in, pair_tok, pair_w);
    combine_k<<<T_TOK, 256, 0, stream>>>(O, pairidx, out);
  } else {
    hipMemsetAsync(out, 0, (size_t)T_TOK * H_DIM * 4, stream);
    gemm2_k<true><<<dim3(H_DIM / 64, 4, E_NUM), 512, 0, stream>>>(
        w2, H1, out, out, cnt, offs, amax2, s2in, pair_tok, pair_w);
  }
}

// Round 5
// 233.163 us; speedup vs baseline: 1.9689x; 1.0656x over previous
//
#include <hip/hip_runtime.h>
#include <cstdint>
#include <cstddef>

#define T_TOK 1024
#define H_DIM 1024
#define I_DIM 2816
#define E_NUM 8
#define PAIRS 2048  // T_TOK * top_k(=2)

typedef __attribute__((ext_vector_type(4))) float f32x4;
typedef __attribute__((ext_vector_type(4))) unsigned int u32x4;
typedef __attribute__((ext_vector_type(2))) unsigned int u32x2;
typedef long i64;

// ---------- fp8 e4m3fn encode ----------
__device__ __forceinline__ unsigned char fp8e4m3_sw(float v) {
  v = fminf(448.f, fmaxf(-448.f, v));
  unsigned b = __float_as_uint(v);
  unsigned s = (b >> 24) & 0x80u;
  float a = fabsf(v);
  if (a < 0.015625f) {
    int m = (int)rintf(a * 512.f);
    return (unsigned char)(s | (unsigned)m);
  }
  unsigned ab = b & 0x7fffffffu;
  unsigned rnd = 0x7FFFFu + ((ab >> 20) & 1u);
  ab += rnd;
  int e = (int)(ab >> 23) - 127;
  unsigned m = (ab >> 20) & 7u;
  if (e > 8 || (e == 8 && m > 6)) { e = 8; m = 6; }
  return (unsigned char)(s | (unsigned)((e + 7) << 3) | m);
}

__device__ __forceinline__ unsigned q4(float a, float b, float c, float d) {
#if __has_builtin(__builtin_amdgcn_cvt_pk_fp8_f32)
  unsigned w = (unsigned)__builtin_amdgcn_cvt_pk_fp8_f32(a, b, 0, false);
  return (unsigned)__builtin_amdgcn_cvt_pk_fp8_f32(c, d, (int)w, true);
#else
  return (unsigned)fp8e4m3_sw(a) | ((unsigned)fp8e4m3_sw(b) << 8) |
         ((unsigned)fp8e4m3_sw(c) << 16) | ((unsigned)fp8e4m3_sw(d) << 24);
#endif
}

__device__ __forceinline__ unsigned char q1(float a) {
#if __has_builtin(__builtin_amdgcn_cvt_pk_fp8_f32)
  return (unsigned char)((unsigned)__builtin_amdgcn_cvt_pk_fp8_f32(a, a, 0, false) & 0xFFu);
#else
  return fp8e4m3_sw(a);
#endif
}

__device__ __forceinline__ unsigned q4v(float4 f, float inv) {
  return q4(f.x * inv, f.y * inv, f.z * inv, f.w * inv);
}

// ---------- fused routing: zero ctrl + softmax-top2 + counting-sort slots (1 block) ----------
__global__ __launch_bounds__(1024) void route_k(const float* __restrict__ logits,
                                                unsigned* __restrict__ amax13,
                                                unsigned* __restrict__ amax2,
                                                int* __restrict__ cnt_g,
                                                int* __restrict__ offs_g,
                                                int* __restrict__ pair_tok,
                                                float* __restrict__ pair_w,
                                                int* __restrict__ pairidx) {
  __shared__ int cnt_s[E_NUM], pos_s[E_NUM];
  const int tid = threadIdx.x;
  if (tid < E_NUM) { cnt_s[tid] = 0; amax13[tid] = 0; amax2[tid] = 0; }
  __syncthreads();

  float l[E_NUM];
#pragma unroll
  for (int j = 0; j < E_NUM; j++) l[j] = logits[tid * E_NUM + j];
  int i0 = 0; float b0 = l[0];
#pragma unroll
  for (int j = 1; j < E_NUM; j++) { if (l[j] > b0) { b0 = l[j]; i0 = j; } }
  int i1 = -1; float b1 = -3.4e38f;
#pragma unroll
  for (int j = 0; j < E_NUM; j++) { if (j != i0 && l[j] > b1) { b1 = l[j]; i1 = j; } }
  float e1 = expf(b1 - b0);
  float d = 1.f + e1;
  float w0 = 1.f / d, w1 = e1 / d;

  atomicAdd(&cnt_s[i0], 1);
  atomicAdd(&cnt_s[i1], 1);
  __syncthreads();
  if (tid == 0) {
    int s = 0;
#pragma unroll
    for (int e = 0; e < E_NUM; e++) {
      cnt_g[e] = cnt_s[e];
      offs_g[e] = s;
      pos_s[e] = s;
      s += cnt_s[e];
    }
    offs_g[E_NUM] = s;
  }
  __syncthreads();
  int s0 = atomicAdd(&pos_s[i0], 1);
  pair_tok[s0] = tid; pair_w[s0] = w0; pairidx[2 * tid] = s0;
  int s1 = atomicAdd(&pos_s[i1], 1);
  pair_tok[s1] = tid; pair_w[s1] = w1; pairidx[2 * tid + 1] = s1;
}

// ---------- fused per-expert amax over w13 AND w2 (1 atomic per block) ----------
__global__ __launch_bounds__(256) void amax_k(const float* __restrict__ w13,
                                              const float* __restrict__ w2,
                                              unsigned* __restrict__ amax13,
                                              unsigned* __restrict__ amax2) {
  const int e = blockIdx.y;
  const float4* src;
  unsigned* dst;
  int bx = blockIdx.x, nb;
  if (bx < 128) { src = (const float4*)w13 + (size_t)e * (2 * I_DIM * H_DIM / 4); dst = &amax13[e]; nb = 128; }
  else          { src = (const float4*)w2  + (size_t)e * (H_DIM * I_DIM / 4);     dst = &amax2[e];  bx -= 128; nb = 64; }
  int idx = bx * 256 + threadIdx.x;
  int stride = nb * 256;
  float m = 0.f;
#pragma unroll
  for (int j = 0; j < 44; j += 4) {
    float4 v0 = src[idx + (size_t)(j + 0) * stride];
    float4 v1 = src[idx + (size_t)(j + 1) * stride];
    float4 v2 = src[idx + (size_t)(j + 2) * stride];
    float4 v3 = src[idx + (size_t)(j + 3) * stride];
    m = fmaxf(m, fmaxf(fmaxf(fabsf(v0.x), fabsf(v0.y)), fmaxf(fabsf(v0.z), fabsf(v0.w))));
    m = fmaxf(m, fmaxf(fmaxf(fabsf(v1.x), fabsf(v1.y)), fmaxf(fabsf(v1.z), fabsf(v1.w))));
    m = fmaxf(m, fmaxf(fmaxf(fabsf(v2.x), fabsf(v2.y)), fmaxf(fabsf(v2.z), fabsf(v2.w))));
    m = fmaxf(m, fmaxf(fmaxf(fabsf(v3.x), fabsf(v3.y)), fmaxf(fabsf(v3.z), fabsf(v3.w))));
  }
#pragma unroll
  for (int off = 32; off > 0; off >>= 1) m = fmaxf(m, __shfl_xor(m, off));
  __shared__ float wmax[4];
  int lane = threadIdx.x & 63, wid = threadIdx.x >> 6;
  if (lane == 0) wmax[wid] = m;
  __syncthreads();
  if (threadIdx.x == 0) {
    float mm = fmaxf(fmaxf(wmax[0], wmax[1]), fmaxf(wmax[2], wmax[3]));
    atomicMax(dst, __float_as_uint(mm));
  }
}

// ---------- per-pair activation quant ----------
__global__ __launch_bounds__(256) void quantx_k(const float* __restrict__ x,
                                                const int* __restrict__ pair_tok,
                                                const int* __restrict__ offs,
                                                const float* __restrict__ s13,
                                                unsigned char* __restrict__ Xq) {
  int p = blockIdx.x;
  int t = pair_tok[p];
  int e = 0;
#pragma unroll
  for (int j = 1; j < E_NUM; j++) { if (p >= offs[j]) e = j; }
  float inv = 1.f / s13[e];
  float4 v = ((const float4*)(x + (size_t)t * H_DIM))[threadIdx.x];
  float a = fminf(448.f, fmaxf(-448.f, v.x * inv));
  float b = fminf(448.f, fmaxf(-448.f, v.y * inv));
  float c = fminf(448.f, fmaxf(-448.f, v.z * inv));
  float dd = fminf(448.f, fmaxf(-448.f, v.w * inv));
  ((unsigned*)(Xq + (size_t)p * H_DIM))[threadIdx.x] = q4(a, b, c, dd);
}

// ---------- GEMM1: BM=256, BN=32(gate)+32(up), BK=64, 512 threads ----------
// weights read once; raw-load prefetch, quantize AFTER MFMA block (latency hidden)
__global__ __launch_bounds__(512) void gemm1_k(const float* __restrict__ w13,
                                               const unsigned char* __restrict__ Xq,
                                               unsigned char* __restrict__ H1,
                                               const int* __restrict__ cnt,
                                               const int* __restrict__ offs,
                                               const unsigned* __restrict__ amax13,
                                               const float* __restrict__ s13,
                                               const float* __restrict__ s2in) {
  const int e = blockIdx.z;
  const int count = cnt[e];
  const int m0 = blockIdx.y * 256;
  if (m0 >= count) return;
  const int nt = blockIdx.x;  // 0..87, 32 gate + 32 up cols
  const int base = offs[e];

  const float amax = __uint_as_float(amax13[e]);
  const float inv_w = 448.f / amax;
  const float gs = s13[e] * (amax / 448.f);
  const float inv_a2 = 1.f / s2in[e];

  __shared__ __align__(16) unsigned char As[256][80];
  __shared__ __align__(16) unsigned char Bs[64][80];  // rows 0..31 gate, 32..63 up

  const int tid = threadIdx.x, lane = tid & 63, wq = tid >> 6;
  const int fr = lane & 15, ks = lane >> 4;

  f32x4 accg[2][2], accu[2][2];
#pragma unroll
  for (int i = 0; i < 2; i++)
#pragma unroll
    for (int j = 0; j < 2; j++) { accg[i][j] = (f32x4)0.f; accu[i][j] = (f32x4)0.f; }

  // A: 256 rows x 4 segs(16B) = 1024 slots; thread does tid and tid+512
  const int ar0 = tid >> 2, ar1 = (tid + 512) >> 2, aseg = tid & 3;
  int pr0 = base + m0 + ar0; if (pr0 > PAIRS - 1) pr0 = PAIRS - 1;
  int pr1 = base + m0 + ar1; if (pr1 > PAIRS - 1) pr1 = PAIRS - 1;
  const unsigned char* a_src0 = Xq + (size_t)pr0 * H_DIM + aseg * 16;
  const unsigned char* a_src1 = Xq + (size_t)pr1 * H_DIM + aseg * 16;

  // B: 64 rows x 8 segs(8 f32) = 512 slots; brow<32 gate, >=32 up
  const int brow = tid >> 3, bseg = tid & 7;
  const size_t brg = (size_t)nt * 32 + (brow & 31) + (size_t)(brow >> 5) * I_DIM;
  const float* b_src = w13 + ((size_t)e * 2 * I_DIM + brg) * H_DIM + bseg * 8;

  u32x4 ra0 = *(const u32x4*)a_src0;
  u32x4 ra1 = *(const u32x4*)a_src1;
  float4 fb0 = ((const float4*)b_src)[0], fb1 = ((const float4*)b_src)[1];
  unsigned qb0 = q4v(fb0, inv_w), qb1 = q4v(fb1, inv_w);

  for (int t = 0; t < H_DIM / 64; ++t) {
    __syncthreads();
    *(u32x4*)&As[ar0][aseg * 16] = ra0;
    *(u32x4*)&As[ar1][aseg * 16] = ra1;
    ((unsigned*)&Bs[brow][bseg * 8])[0] = qb0;
    ((unsigned*)&Bs[brow][bseg * 8])[1] = qb1;
    __syncthreads();
    if (t + 1 < H_DIM / 64) {  // issue raw loads; quantize after MFMA
      int k0 = (t + 1) * 64;
      ra0 = *(const u32x4*)(a_src0 + k0);
      ra1 = *(const u32x4*)(a_src1 + k0);
      fb0 = ((const float4*)(b_src + k0))[0];
      fb1 = ((const float4*)(b_src + k0))[1];
    }
#pragma unroll
    for (int kk = 0; kk < 2; kk++) {
      i64 a0 = *(const i64*)&As[wq * 32 + fr][kk * 32 + ks * 8];
      i64 a1 = *(const i64*)&As[wq * 32 + 16 + fr][kk * 32 + ks * 8];
#pragma unroll
      for (int ni = 0; ni < 2; ni++) {
        i64 bg = *(const i64*)&Bs[ni * 16 + fr][kk * 32 + ks * 8];
        i64 bu = *(const i64*)&Bs[32 + ni * 16 + fr][kk * 32 + ks * 8];
        accg[0][ni] = __builtin_amdgcn_mfma_f32_16x16x32_fp8_fp8(a0, bg, accg[0][ni], 0, 0, 0);
        accg[1][ni] = __builtin_amdgcn_mfma_f32_16x16x32_fp8_fp8(a1, bg, accg[1][ni], 0, 0, 0);
        accu[0][ni] = __builtin_amdgcn_mfma_f32_16x16x32_fp8_fp8(a0, bu, accu[0][ni], 0, 0, 0);
        accu[1][ni] = __builtin_amdgcn_mfma_f32_16x16x32_fp8_fp8(a1, bu, accu[1][ni], 0, 0, 0);
      }
    }
    qb0 = q4v(fb0, inv_w);  // vmcnt wait lands here, after MFMA block
    qb1 = q4v(fb1, inv_w);
  }

  const int rg = lane >> 4;
#pragma unroll
  for (int mi = 0; mi < 2; mi++) {
#pragma unroll
    for (int rr = 0; rr < 4; rr++) {
      int lrow = wq * 32 + mi * 16 + rg * 4 + rr;
      if (m0 + lrow < count) {
        size_t p = (size_t)(base + m0 + lrow);
#pragma unroll
        for (int ni = 0; ni < 2; ni++) {
          int col = nt * 32 + ni * 16 + fr;
          float g = accg[mi][ni][rr] * gs;
          float u = accu[mi][ni][rr] * gs;
          float act = g / (1.f + expf(-g)) * u * inv_a2;
          act = fminf(448.f, fmaxf(-448.f, act));
          H1[p * I_DIM + col] = q1(act);
        }
      }
    }
  }
}

// ---------- GEMM2: BM=256, BN=32, BK=64, 512 threads ----------
__global__ __launch_bounds__(512) void gemm2_k(const float* __restrict__ w2,
                                               const unsigned char* __restrict__ H1,
                                               float* __restrict__ O,
                                               const int* __restrict__ cnt,
                                               const int* __restrict__ offs,
                                               const unsigned* __restrict__ amax2,
                                               const float* __restrict__ s2in,
                                               const float* __restrict__ pair_w) {
  const int e = blockIdx.z;
  const int count = cnt[e];
  const int m0 = blockIdx.y * 256;
  if (m0 >= count) return;
  const int n0 = blockIdx.x * 32;
  const int base = offs[e];

  const float amax = __uint_as_float(amax2[e]);
  const float inv_w = 448.f / amax;
  const float s2 = s2in[e] * (amax / 448.f);

  __shared__ __align__(16) unsigned char As[256][80];
  __shared__ __align__(16) unsigned char Bs[32][80];

  const int tid = threadIdx.x, lane = tid & 63, wq = tid >> 6;
  const int fr = lane & 15, ks = lane >> 4;

  f32x4 acc[2][2];
#pragma unroll
  for (int i = 0; i < 2; i++)
#pragma unroll
    for (int j = 0; j < 2; j++) acc[i][j] = (f32x4)0.f;

  const int ar0 = tid >> 2, ar1 = (tid + 512) >> 2, aseg = tid & 3;
  int pr0 = base + m0 + ar0; if (pr0 > PAIRS - 1) pr0 = PAIRS - 1;
  int pr1 = base + m0 + ar1; if (pr1 > PAIRS - 1) pr1 = PAIRS - 1;
  const unsigned char* a_src0 = H1 + (size_t)pr0 * I_DIM + aseg * 16;
  const unsigned char* a_src1 = H1 + (size_t)pr1 * I_DIM + aseg * 16;

  // B: 32 rows x 16 segs(4 f32) = 512 slots
  const int brow = tid >> 4, bseg = tid & 15;
  const float* b_src = w2 + ((size_t)e * H_DIM + n0 + brow) * I_DIM + bseg * 4;

  u32x4 ra0 = *(const u32x4*)a_src0;
  u32x4 ra1 = *(const u32x4*)a_src1;
  float4 fb = ((const float4*)b_src)[0];
  unsigned qb = q4v(fb, inv_w);

  for (int t = 0; t < I_DIM / 64; ++t) {
    __syncthreads();
    *(u32x4*)&As[ar0][aseg * 16] = ra0;
    *(u32x4*)&As[ar1][aseg * 16] = ra1;
    *(unsigned*)&Bs[brow][bseg * 4] = qb;
    __syncthreads();
    if (t + 1 < I_DIM / 64) {
      int k0 = (t + 1) * 64;
      ra0 = *(const u32x4*)(a_src0 + k0);
      ra1 = *(const u32x4*)(a_src1 + k0);
      fb = ((const float4*)(b_src + k0))[0];
    }
#pragma unroll
    for (int kk = 0; kk < 2; kk++) {
      i64 a0 = *(const i64*)&As[wq * 32 + fr][kk * 32 + ks * 8];
      i64 a1 = *(const i64*)&As[wq * 32 + 16 + fr][kk * 32 + ks * 8];
#pragma unroll
      for (int ni = 0; ni < 2; ni++) {
        i64 b = *(const i64*)&Bs[ni * 16 + fr][kk * 32 + ks * 8];
        acc[0][ni] = __builtin_amdgcn_mfma_f32_16x16x32_fp8_fp8(a0, b, acc[0][ni], 0, 0, 0);
        acc[1][ni] = __builtin_amdgcn_mfma_f32_16x16x32_fp8_fp8(a1, b, acc[1][ni], 0, 0, 0);
      }
    }
    qb = q4v(fb, inv_w);
  }

  const int rg = lane >> 4;
#pragma unroll
  for (int mi = 0; mi < 2; mi++) {
#pragma unroll
    for (int rr = 0; rr < 4; rr++) {
      int lrow = wq * 32 + mi * 16 + rg * 4 + rr;
      if (m0 + lrow < count) {
        size_t p = (size_t)(base + m0 + lrow);
        float pw = pair_w[p];
#pragma unroll
        for (int ni = 0; ni < 2; ni++) {
          int col = n0 + ni * 16 + fr;
          O[p * H_DIM + col] = acc[mi][ni][rr] * s2 * pw;
        }
      }
    }
  }
}

// ---------- combine ----------
__global__ __launch_bounds__(256) void combine_k(const float* __restrict__ O,
                                                 const int* __restrict__ pairidx,
                                                 float* __restrict__ out) {
  int t = blockIdx.x;
  int p0 = pairidx[2 * t], p1 = pairidx[2 * t + 1];
  float4 a = ((const float4*)(O + (size_t)p0 * H_DIM))[threadIdx.x];
  float4 b = ((const float4*)(O + (size_t)p1 * H_DIM))[threadIdx.x];
  float4 r;
  r.x = a.x + b.x; r.y = a.y + b.y; r.z = a.z + b.z; r.w = a.w + b.w;
  ((float4*)(out + (size_t)t * H_DIM))[threadIdx.x] = r;
}

extern "C" void kernel_launch(void* const* d_in, const int* in_sizes, int n_in,
                              void* d_out, int out_size, void* d_ws, size_t ws_size,
                              hipStream_t stream) {
  (void)in_sizes; (void)n_in; (void)out_size; (void)ws_size;
  const float* x      = (const float*)d_in[0];
  const float* logits = (const float*)d_in[1];
  const float* w13    = (const float*)d_in[2];
  const float* w2     = (const float*)d_in[3];
  const float* s13    = (const float*)d_in[4];
  const float* s2in   = (const float*)d_in[5];
  float* out = (float*)d_out;

  char* ws = (char*)d_ws;
  unsigned* amax13 = (unsigned*)(ws + 0);
  unsigned* amax2  = (unsigned*)(ws + 64);
  int* cnt     = (int*)(ws + 128);
  int* offs    = (int*)(ws + 192);
  int* pair_tok = (int*)(ws + 17408);
  float* pair_w = (float*)(ws + 25600);
  int* pairidx  = (int*)(ws + 33792);
  unsigned char* Xq = (unsigned char*)(ws + (size_t)(1 << 20));        // 2 MB
  unsigned char* H1 = (unsigned char*)(ws + (size_t)4 * (1 << 20));    // 5.77 MB
  float* O          = (float*)(ws + (size_t)10 * (1 << 20));           // 8 MB

  route_k<<<1, 1024, 0, stream>>>(logits, amax13, amax2, cnt, offs,
                                  pair_tok, pair_w, pairidx);

  amax_k<<<dim3(192, E_NUM), 256, 0, stream>>>(w13, w2, amax13, amax2);

  quantx_k<<<PAIRS, 256, 0, stream>>>(x, pair_tok, offs, s13, Xq);

  gemm1_k<<<dim3(I_DIM / 32, 4, E_NUM), 512, 0, stream>>>(
      w13, Xq, H1, cnt, offs, amax13, s13, s2in);

  gemm2_k<<<dim3(H_DIM / 32, 4, E_NUM), 512, 0, stream>>>(
      w2, H1, O, cnt, offs, amax2, s2in, pair_w);

  combine_k<<<T_TOK, 256, 0, stream>>>(O, pairidx, out);
}

// Round 6
// 171.711 us; speedup vs baseline: 2.6736x; 1.3579x over previous
//
#include <hip/hip_runtime.h>
#include <cstdint>
#include <cstddef>

#define T_TOK 1024
#define H_DIM 1024
#define I_DIM 2816
#define E_NUM 8
#define PAIRS 2048  // T_TOK * top_k(=2)
#define KSPLIT 4    // gemm2 split-K factor (44 BK-iters -> 11 per split)

typedef __attribute__((ext_vector_type(4))) float f32x4;
typedef __attribute__((ext_vector_type(4))) unsigned int u32x4;
typedef long i64;

// ---------- fp8 e4m3fn encode ----------
__device__ __forceinline__ unsigned char fp8e4m3_sw(float v) {
  v = fminf(448.f, fmaxf(-448.f, v));
  unsigned b = __float_as_uint(v);
  unsigned s = (b >> 24) & 0x80u;
  float a = fabsf(v);
  if (a < 0.015625f) {
    int m = (int)rintf(a * 512.f);
    return (unsigned char)(s | (unsigned)m);
  }
  unsigned ab = b & 0x7fffffffu;
  unsigned rnd = 0x7FFFFu + ((ab >> 20) & 1u);
  ab += rnd;
  int e = (int)(ab >> 23) - 127;
  unsigned m = (ab >> 20) & 7u;
  if (e > 8 || (e == 8 && m > 6)) { e = 8; m = 6; }
  return (unsigned char)(s | (unsigned)((e + 7) << 3) | m);
}

__device__ __forceinline__ unsigned q4(float a, float b, float c, float d) {
#if __has_builtin(__builtin_amdgcn_cvt_pk_fp8_f32)
  unsigned w = (unsigned)__builtin_amdgcn_cvt_pk_fp8_f32(a, b, 0, false);
  return (unsigned)__builtin_amdgcn_cvt_pk_fp8_f32(c, d, (int)w, true);
#else
  return (unsigned)fp8e4m3_sw(a) | ((unsigned)fp8e4m3_sw(b) << 8) |
         ((unsigned)fp8e4m3_sw(c) << 16) | ((unsigned)fp8e4m3_sw(d) << 24);
#endif
}

__device__ __forceinline__ unsigned char q1(float a) {
#if __has_builtin(__builtin_amdgcn_cvt_pk_fp8_f32)
  return (unsigned char)((unsigned)__builtin_amdgcn_cvt_pk_fp8_f32(a, a, 0, false) & 0xFFu);
#else
  return fp8e4m3_sw(a);
#endif
}

__device__ __forceinline__ unsigned q4v(float4 f, float inv) {
  return q4(f.x * inv, f.y * inv, f.z * inv, f.w * inv);
}

// ---------- fused routing: zero ctrl + softmax-top2 + counting-sort slots (1 block) ----------
__global__ __launch_bounds__(1024) void route_k(const float* __restrict__ logits,
                                                unsigned* __restrict__ amax13,
                                                unsigned* __restrict__ amax2,
                                                int* __restrict__ cnt_g,
                                                int* __restrict__ offs_g,
                                                int* __restrict__ pair_tok,
                                                float* __restrict__ pair_w,
                                                int* __restrict__ pairidx) {
  __shared__ int cnt_s[E_NUM], pos_s[E_NUM];
  const int tid = threadIdx.x;
  if (tid < E_NUM) { cnt_s[tid] = 0; amax13[tid] = 0; amax2[tid] = 0; }
  __syncthreads();

  float l[E_NUM];
#pragma unroll
  for (int j = 0; j < E_NUM; j++) l[j] = logits[tid * E_NUM + j];
  int i0 = 0; float b0 = l[0];
#pragma unroll
  for (int j = 1; j < E_NUM; j++) { if (l[j] > b0) { b0 = l[j]; i0 = j; } }
  int i1 = -1; float b1 = -3.4e38f;
#pragma unroll
  for (int j = 0; j < E_NUM; j++) { if (j != i0 && l[j] > b1) { b1 = l[j]; i1 = j; } }
  float e1 = expf(b1 - b0);
  float d = 1.f + e1;
  float w0 = 1.f / d, w1 = e1 / d;

  atomicAdd(&cnt_s[i0], 1);
  atomicAdd(&cnt_s[i1], 1);
  __syncthreads();
  if (tid == 0) {
    int s = 0;
#pragma unroll
    for (int e = 0; e < E_NUM; e++) {
      cnt_g[e] = cnt_s[e];
      offs_g[e] = s;
      pos_s[e] = s;
      s += cnt_s[e];
    }
    offs_g[E_NUM] = s;
  }
  __syncthreads();
  int s0 = atomicAdd(&pos_s[i0], 1);
  pair_tok[s0] = tid; pair_w[s0] = w0; pairidx[2 * tid] = s0;
  int s1 = atomicAdd(&pos_s[i1], 1);
  pair_tok[s1] = tid; pair_w[s1] = w1; pairidx[2 * tid + 1] = s1;
}

// ---------- fused per-expert amax over w13 AND w2 (1 atomic per block) ----------
__global__ __launch_bounds__(256) void amax_k(const float* __restrict__ w13,
                                              const float* __restrict__ w2,
                                              unsigned* __restrict__ amax13,
                                              unsigned* __restrict__ amax2) {
  const int e = blockIdx.y;
  const float4* src;
  unsigned* dst;
  int bx = blockIdx.x, nb;
  if (bx < 128) { src = (const float4*)w13 + (size_t)e * (2 * I_DIM * H_DIM / 4); dst = &amax13[e]; nb = 128; }
  else          { src = (const float4*)w2  + (size_t)e * (H_DIM * I_DIM / 4);     dst = &amax2[e];  bx -= 128; nb = 64; }
  int idx = bx * 256 + threadIdx.x;
  int stride = nb * 256;
  float m = 0.f;
#pragma unroll
  for (int j = 0; j < 44; j += 4) {
    float4 v0 = src[idx + (size_t)(j + 0) * stride];
    float4 v1 = src[idx + (size_t)(j + 1) * stride];
    float4 v2 = src[idx + (size_t)(j + 2) * stride];
    float4 v3 = src[idx + (size_t)(j + 3) * stride];
    m = fmaxf(m, fmaxf(fmaxf(fabsf(v0.x), fabsf(v0.y)), fmaxf(fabsf(v0.z), fabsf(v0.w))));
    m = fmaxf(m, fmaxf(fmaxf(fabsf(v1.x), fabsf(v1.y)), fmaxf(fabsf(v1.z), fabsf(v1.w))));
    m = fmaxf(m, fmaxf(fmaxf(fabsf(v2.x), fabsf(v2.y)), fmaxf(fabsf(v2.z), fabsf(v2.w))));
    m = fmaxf(m, fmaxf(fmaxf(fabsf(v3.x), fabsf(v3.y)), fmaxf(fabsf(v3.z), fabsf(v3.w))));
  }
#pragma unroll
  for (int off = 32; off > 0; off >>= 1) m = fmaxf(m, __shfl_xor(m, off));
  __shared__ float wmax[4];
  int lane = threadIdx.x & 63, wid = threadIdx.x >> 6;
  if (lane == 0) wmax[wid] = m;
  __syncthreads();
  if (threadIdx.x == 0) {
    float mm = fmaxf(fmaxf(wmax[0], wmax[1]), fmaxf(wmax[2], wmax[3]));
    atomicMax(dst, __float_as_uint(mm));
  }
}

// ---------- per-pair activation quant ----------
__global__ __launch_bounds__(256) void quantx_k(const float* __restrict__ x,
                                                const int* __restrict__ pair_tok,
                                                const int* __restrict__ offs,
                                                const float* __restrict__ s13,
                                                unsigned char* __restrict__ Xq) {
  int p = blockIdx.x;
  int t = pair_tok[p];
  int e = 0;
#pragma unroll
  for (int j = 1; j < E_NUM; j++) { if (p >= offs[j]) e = j; }
  float inv = 1.f / s13[e];
  float4 v = ((const float4*)(x + (size_t)t * H_DIM))[threadIdx.x];
  float a = fminf(448.f, fmaxf(-448.f, v.x * inv));
  float b = fminf(448.f, fmaxf(-448.f, v.y * inv));
  float c = fminf(448.f, fmaxf(-448.f, v.z * inv));
  float dd = fminf(448.f, fmaxf(-448.f, v.w * inv));
  ((unsigned*)(Xq + (size_t)p * H_DIM))[threadIdx.x] = q4(a, b, c, dd);
}

// ---------- GEMM1: BM=256, BN=32(gate)+32(up), BK=64, 512 threads ----------
__global__ __launch_bounds__(512) void gemm1_k(const float* __restrict__ w13,
                                               const unsigned char* __restrict__ Xq,
                                               unsigned char* __restrict__ H1,
                                               const int* __restrict__ cnt,
                                               const int* __restrict__ offs,
                                               const unsigned* __restrict__ amax13,
                                               const float* __restrict__ s13,
                                               const float* __restrict__ s2in) {
  const int e = blockIdx.z;
  const int count = cnt[e];
  const int m0 = blockIdx.y * 256;
  if (m0 >= count) return;
  const int nt = blockIdx.x;  // 0..87, 32 gate + 32 up cols
  const int base = offs[e];

  const float amax = __uint_as_float(amax13[e]);
  const float inv_w = 448.f / amax;
  const float gs = s13[e] * (amax / 448.f);
  const float inv_a2 = 1.f / s2in[e];

  __shared__ __align__(16) unsigned char As[256][80];
  __shared__ __align__(16) unsigned char Bs[64][80];  // rows 0..31 gate, 32..63 up

  const int tid = threadIdx.x, lane = tid & 63, wq = tid >> 6;
  const int fr = lane & 15, ks = lane >> 4;

  f32x4 accg[2][2], accu[2][2];
#pragma unroll
  for (int i = 0; i < 2; i++)
#pragma unroll
    for (int j = 0; j < 2; j++) { accg[i][j] = (f32x4)0.f; accu[i][j] = (f32x4)0.f; }

  const int ar0 = tid >> 2, ar1 = (tid + 512) >> 2, aseg = tid & 3;
  int pr0 = base + m0 + ar0; if (pr0 > PAIRS - 1) pr0 = PAIRS - 1;
  int pr1 = base + m0 + ar1; if (pr1 > PAIRS - 1) pr1 = PAIRS - 1;
  const unsigned char* a_src0 = Xq + (size_t)pr0 * H_DIM + aseg * 16;
  const unsigned char* a_src1 = Xq + (size_t)pr1 * H_DIM + aseg * 16;

  const int brow = tid >> 3, bseg = tid & 7;
  const size_t brg = (size_t)nt * 32 + (brow & 31) + (size_t)(brow >> 5) * I_DIM;
  const float* b_src = w13 + ((size_t)e * 2 * I_DIM + brg) * H_DIM + bseg * 8;

  u32x4 ra0 = *(const u32x4*)a_src0;
  u32x4 ra1 = *(const u32x4*)a_src1;
  float4 fb0 = ((const float4*)b_src)[0], fb1 = ((const float4*)b_src)[1];
  unsigned qb0 = q4v(fb0, inv_w), qb1 = q4v(fb1, inv_w);

  for (int t = 0; t < H_DIM / 64; ++t) {
    __syncthreads();
    *(u32x4*)&As[ar0][aseg * 16] = ra0;
    *(u32x4*)&As[ar1][aseg * 16] = ra1;
    ((unsigned*)&Bs[brow][bseg * 8])[0] = qb0;
    ((unsigned*)&Bs[brow][bseg * 8])[1] = qb1;
    __syncthreads();
    if (t + 1 < H_DIM / 64) {
      int k0 = (t + 1) * 64;
      ra0 = *(const u32x4*)(a_src0 + k0);
      ra1 = *(const u32x4*)(a_src1 + k0);
      fb0 = ((const float4*)(b_src + k0))[0];
      fb1 = ((const float4*)(b_src + k0))[1];
    }
#pragma unroll
    for (int kk = 0; kk < 2; kk++) {
      i64 a0 = *(const i64*)&As[wq * 32 + fr][kk * 32 + ks * 8];
      i64 a1 = *(const i64*)&As[wq * 32 + 16 + fr][kk * 32 + ks * 8];
#pragma unroll
      for (int ni = 0; ni < 2; ni++) {
        i64 bg = *(const i64*)&Bs[ni * 16 + fr][kk * 32 + ks * 8];
        i64 bu = *(const i64*)&Bs[32 + ni * 16 + fr][kk * 32 + ks * 8];
        accg[0][ni] = __builtin_amdgcn_mfma_f32_16x16x32_fp8_fp8(a0, bg, accg[0][ni], 0, 0, 0);
        accg[1][ni] = __builtin_amdgcn_mfma_f32_16x16x32_fp8_fp8(a1, bg, accg[1][ni], 0, 0, 0);
        accu[0][ni] = __builtin_amdgcn_mfma_f32_16x16x32_fp8_fp8(a0, bu, accu[0][ni], 0, 0, 0);
        accu[1][ni] = __builtin_amdgcn_mfma_f32_16x16x32_fp8_fp8(a1, bu, accu[1][ni], 0, 0, 0);
      }
    }
    qb0 = q4v(fb0, inv_w);  // vmcnt wait lands here, after MFMA block
    qb1 = q4v(fb1, inv_w);
  }

  const int rg = lane >> 4;
#pragma unroll
  for (int mi = 0; mi < 2; mi++) {
#pragma unroll
    for (int rr = 0; rr < 4; rr++) {
      int lrow = wq * 32 + mi * 16 + rg * 4 + rr;
      if (m0 + lrow < count) {
        size_t p = (size_t)(base + m0 + lrow);
#pragma unroll
        for (int ni = 0; ni < 2; ni++) {
          int col = nt * 32 + ni * 16 + fr;
          float g = accg[mi][ni][rr] * gs;
          float u = accu[mi][ni][rr] * gs;
          float act = g / (1.f + expf(-g)) * u * inv_a2;
          act = fminf(448.f, fmaxf(-448.f, act));
          H1[p * I_DIM + col] = q1(act);
        }
      }
    }
  }
}

// ---------- GEMM2: split-K, BM=128, BN=64, BK=64, 512 threads ----------
// grid.x = 16 n-tiles * KSPLIT; each block does (I_DIM/64)/KSPLIT K-iters,
// writes f32 partials Op[ksp][pair][H]. Deterministic (no atomics).
__global__ __launch_bounds__(512) void gemm2_k(const float* __restrict__ w2,
                                               const unsigned char* __restrict__ H1,
                                               float* __restrict__ Op,
                                               const int* __restrict__ cnt,
                                               const int* __restrict__ offs,
                                               const unsigned* __restrict__ amax2,
                                               const float* __restrict__ s2in,
                                               const float* __restrict__ pair_w) {
  const int e = blockIdx.z;
  const int count = cnt[e];
  const int m0 = blockIdx.y * 128;
  if (m0 >= count) return;
  const int nt = blockIdx.x & 15;
  const int ksp = blockIdx.x >> 4;
  const int n0 = nt * 64;
  const int base = offs[e];

  const float amax = __uint_as_float(amax2[e]);
  const float inv_w = 448.f / amax;
  const float s2 = s2in[e] * (amax / 448.f);

  __shared__ __align__(16) unsigned char As[128][80];
  __shared__ __align__(16) unsigned char Bs[64][80];

  const int tid = threadIdx.x, lane = tid & 63, wq = tid >> 6;
  const int fr = lane & 15, ks = lane >> 4;

  f32x4 acc[4];
#pragma unroll
  for (int i = 0; i < 4; i++) acc[i] = (f32x4)0.f;

  // A: 128 rows x 4 segs(16B) = 512 slots
  const int arow = tid >> 2, aseg = tid & 3;
  int pr = base + m0 + arow; if (pr > PAIRS - 1) pr = PAIRS - 1;
  const unsigned char* a_src = H1 + (size_t)pr * I_DIM + aseg * 16;

  // B: 64 rows x 8 segs(8 f32 -> 8B fp8) = 512 slots
  const int brow = tid >> 3, bseg = tid & 7;
  const float* b_src = w2 + ((size_t)e * H_DIM + n0 + brow) * I_DIM + bseg * 8;

  const int KITER = (I_DIM / 64) / KSPLIT;  // 11
  const int kbase = ksp * KITER * 64;

  u32x4 ra = *(const u32x4*)(a_src + kbase);
  float4 fb0 = ((const float4*)(b_src + kbase))[0];
  float4 fb1 = ((const float4*)(b_src + kbase))[1];
  unsigned qb0 = q4v(fb0, inv_w), qb1 = q4v(fb1, inv_w);

  for (int t = 0; t < KITER; ++t) {
    __syncthreads();
    *(u32x4*)&As[arow][aseg * 16] = ra;
    ((unsigned*)&Bs[brow][bseg * 8])[0] = qb0;
    ((unsigned*)&Bs[brow][bseg * 8])[1] = qb1;
    __syncthreads();
    if (t + 1 < KITER) {
      int k0 = kbase + (t + 1) * 64;
      ra = *(const u32x4*)(a_src + k0);
      fb0 = ((const float4*)(b_src + k0))[0];
      fb1 = ((const float4*)(b_src + k0))[1];
    }
#pragma unroll
    for (int kk = 0; kk < 2; kk++) {
      i64 a0 = *(const i64*)&As[wq * 16 + fr][kk * 32 + ks * 8];
#pragma unroll
      for (int ni = 0; ni < 4; ni++) {
        i64 b = *(const i64*)&Bs[ni * 16 + fr][kk * 32 + ks * 8];
        acc[ni] = __builtin_amdgcn_mfma_f32_16x16x32_fp8_fp8(a0, b, acc[ni], 0, 0, 0);
      }
    }
    qb0 = q4v(fb0, inv_w);  // vmcnt wait after MFMA block
    qb1 = q4v(fb1, inv_w);
  }

  const int rg = lane >> 4;
#pragma unroll
  for (int rr = 0; rr < 4; rr++) {
    int lrow = wq * 16 + rg * 4 + rr;
    if (m0 + lrow < count) {
      size_t p = (size_t)(base + m0 + lrow);
      float pw = pair_w[p];
#pragma unroll
      for (int ni = 0; ni < 4; ni++) {
        int col = n0 + ni * 16 + fr;
        Op[((size_t)ksp * PAIRS + p) * H_DIM + col] = acc[ni][rr] * s2 * pw;
      }
    }
  }
}

// ---------- combine: out[t,:] = sum over 2 pairs x KSPLIT partials (fixed order) ----------
__global__ __launch_bounds__(256) void combine_k(const float* __restrict__ Op,
                                                 const int* __restrict__ pairidx,
                                                 float* __restrict__ out) {
  int t = blockIdx.x;
  int p0 = pairidx[2 * t], p1 = pairidx[2 * t + 1];
  f32x4 acc = (f32x4)0.f;
#pragma unroll
  for (int s = 0; s < KSPLIT; s++) {
    f32x4 a = ((const f32x4*)(Op + ((size_t)s * PAIRS + p0) * H_DIM))[threadIdx.x];
    f32x4 b = ((const f32x4*)(Op + ((size_t)s * PAIRS + p1) * H_DIM))[threadIdx.x];
    acc += a + b;
  }
  ((f32x4*)(out + (size_t)t * H_DIM))[threadIdx.x] = acc;
}

extern "C" void kernel_launch(void* const* d_in, const int* in_sizes, int n_in,
                              void* d_out, int out_size, void* d_ws, size_t ws_size,
                              hipStream_t stream) {
  (void)in_sizes; (void)n_in; (void)out_size; (void)ws_size;
  const float* x      = (const float*)d_in[0];
  const float* logits = (const float*)d_in[1];
  const float* w13    = (const float*)d_in[2];
  const float* w2     = (const float*)d_in[3];
  const float* s13    = (const float*)d_in[4];
  const float* s2in   = (const float*)d_in[5];
  float* out = (float*)d_out;

  char* ws = (char*)d_ws;
  unsigned* amax13 = (unsigned*)(ws + 0);
  unsigned* amax2  = (unsigned*)(ws + 64);
  int* cnt     = (int*)(ws + 128);
  int* offs    = (int*)(ws + 192);
  int* pair_tok = (int*)(ws + 17408);
  float* pair_w = (float*)(ws + 25600);
  int* pairidx  = (int*)(ws + 33792);
  unsigned char* Xq = (unsigned char*)(ws + (size_t)(1 << 20));        // 2 MB
  unsigned char* H1 = (unsigned char*)(ws + (size_t)4 * (1 << 20));    // 5.77 MB
  float* Op         = (float*)(ws + (size_t)10 * (1 << 20));           // KSPLIT*8 MB

  route_k<<<1, 1024, 0, stream>>>(logits, amax13, amax2, cnt, offs,
                                  pair_tok, pair_w, pairidx);

  amax_k<<<dim3(192, E_NUM), 256, 0, stream>>>(w13, w2, amax13, amax2);

  quantx_k<<<PAIRS, 256, 0, stream>>>(x, pair_tok, offs, s13, Xq);

  gemm1_k<<<dim3(I_DIM / 32, 4, E_NUM), 512, 0, stream>>>(
      w13, Xq, H1, cnt, offs, amax13, s13, s2in);

  gemm2_k<<<dim3(16 * KSPLIT, 8, E_NUM), 512, 0, stream>>>(
      w2, H1, Op, cnt, offs, amax2, s2in, pair_w);

  combine_k<<<T_TOK, 256, 0, stream>>>(Op, pairidx, out);
}

// Round 8
// 165.431 us; speedup vs baseline: 2.7751x; 1.0380x over previous
//
#include <hip/hip_runtime.h>
#include <cstdint>
#include <cstddef>

#define T_TOK 1024
#define H_DIM 1024
#define I_DIM 2816
#define E_NUM 8
#define PAIRS 2048  // T_TOK * top_k(=2)
#define KSPLIT 4    // gemm2 split-K factor (44 BK-iters -> 11 per split)
#define NT1 (I_DIM / 32)   // 88 gemm1 n-tiles
#define AMX2_BLKS 128      // embedded amax2 blocks per expert inside gemm1 grid

typedef __attribute__((ext_vector_type(4))) float f32x4;
typedef __attribute__((ext_vector_type(4))) unsigned int u32x4;
typedef long i64;

// ---------- fp8 e4m3fn encode ----------
__device__ __forceinline__ unsigned char fp8e4m3_sw(float v) {
  v = fminf(448.f, fmaxf(-448.f, v));
  unsigned b = __float_as_uint(v);
  unsigned s = (b >> 24) & 0x80u;
  float a = fabsf(v);
  if (a < 0.015625f) {
    int m = (int)rintf(a * 512.f);
    return (unsigned char)(s | (unsigned)m);
  }
  unsigned ab = b & 0x7fffffffu;
  unsigned rnd = 0x7FFFFu + ((ab >> 20) & 1u);
  ab += rnd;
  int e = (int)(ab >> 23) - 127;
  unsigned m = (ab >> 20) & 7u;
  if (e > 8 || (e == 8 && m > 6)) { e = 8; m = 6; }
  return (unsigned char)(s | (unsigned)((e + 7) << 3) | m);
}

__device__ __forceinline__ unsigned q4(float a, float b, float c, float d) {
#if __has_builtin(__builtin_amdgcn_cvt_pk_fp8_f32)
  unsigned w = (unsigned)__builtin_amdgcn_cvt_pk_fp8_f32(a, b, 0, false);
  return (unsigned)__builtin_amdgcn_cvt_pk_fp8_f32(c, d, (int)w, true);
#else
  return (unsigned)fp8e4m3_sw(a) | ((unsigned)fp8e4m3_sw(b) << 8) |
         ((unsigned)fp8e4m3_sw(c) << 16) | ((unsigned)fp8e4m3_sw(d) << 24);
#endif
}

__device__ __forceinline__ unsigned char q1(float a) {
#if __has_builtin(__builtin_amdgcn_cvt_pk_fp8_f32)
  return (unsigned char)((unsigned)__builtin_amdgcn_cvt_pk_fp8_f32(a, a, 0, false) & 0xFFu);
#else
  return fp8e4m3_sw(a);
#endif
}

__device__ __forceinline__ unsigned q4v(float4 f, float inv) {
  return q4(f.x * inv, f.y * inv, f.z * inv, f.w * inv);
}

// ---------- fused routing: zero ctrl + softmax-top2 + counting-sort slots (1 block) ----------
__global__ __launch_bounds__(1024) void route_k(const float* __restrict__ logits,
                                                unsigned* __restrict__ amax13,
                                                unsigned* __restrict__ amax2,
                                                int* __restrict__ cnt_g,
                                                int* __restrict__ offs_g,
                                                int* __restrict__ pair_tok,
                                                float* __restrict__ pair_w,
                                                int* __restrict__ pairidx) {
  __shared__ int cnt_s[E_NUM], pos_s[E_NUM];
  const int tid = threadIdx.x;
  if (tid < E_NUM) { cnt_s[tid] = 0; amax13[tid] = 0; amax2[tid] = 0; }
  __syncthreads();

  float l[E_NUM];
#pragma unroll
  for (int j = 0; j < E_NUM; j++) l[j] = logits[tid * E_NUM + j];
  int i0 = 0; float b0 = l[0];
#pragma unroll
  for (int j = 1; j < E_NUM; j++) { if (l[j] > b0) { b0 = l[j]; i0 = j; } }
  int i1 = -1; float b1 = -3.4e38f;
#pragma unroll
  for (int j = 0; j < E_NUM; j++) { if (j != i0 && l[j] > b1) { b1 = l[j]; i1 = j; } }
  float e1 = expf(b1 - b0);
  float d = 1.f + e1;
  float w0 = 1.f / d, w1 = e1 / d;

  atomicAdd(&cnt_s[i0], 1);
  atomicAdd(&cnt_s[i1], 1);
  __syncthreads();
  if (tid == 0) {
    int s = 0;
#pragma unroll
    for (int e = 0; e < E_NUM; e++) {
      cnt_g[e] = cnt_s[e];
      offs_g[e] = s;
      pos_s[e] = s;
      s += cnt_s[e];
    }
    offs_g[E_NUM] = s;
  }
  __syncthreads();
  int s0 = atomicAdd(&pos_s[i0], 1);
  pair_tok[s0] = tid; pair_w[s0] = w0; pairidx[2 * tid] = s0;
  int s1 = atomicAdd(&pos_s[i1], 1);
  pair_tok[s1] = tid; pair_w[s1] = w1; pairidx[2 * tid + 1] = s1;
}

// ---------- amax over w13 only (runs right before gemm1 -> LLC-warm w13) ----------
__global__ __launch_bounds__(256) void amax13_k(const float* __restrict__ w13,
                                                unsigned* __restrict__ amax13) {
  const int e = blockIdx.y;
  const float4* src = (const float4*)w13 + (size_t)e * (2 * I_DIM * H_DIM / 4);
  int idx = blockIdx.x * 256 + threadIdx.x;
  int stride = gridDim.x * 256;
  float m = 0.f;
#pragma unroll
  for (int j = 0; j < 44; j += 4) {
    float4 v0 = src[idx + (size_t)(j + 0) * stride];
    float4 v1 = src[idx + (size_t)(j + 1) * stride];
    float4 v2 = src[idx + (size_t)(j + 2) * stride];
    float4 v3 = src[idx + (size_t)(j + 3) * stride];
    m = fmaxf(m, fmaxf(fmaxf(fabsf(v0.x), fabsf(v0.y)), fmaxf(fabsf(v0.z), fabsf(v0.w))));
    m = fmaxf(m, fmaxf(fmaxf(fabsf(v1.x), fabsf(v1.y)), fmaxf(fabsf(v1.z), fabsf(v1.w))));
    m = fmaxf(m, fmaxf(fmaxf(fabsf(v2.x), fabsf(v2.y)), fmaxf(fabsf(v2.z), fabsf(v2.w))));
    m = fmaxf(m, fmaxf(fmaxf(fabsf(v3.x), fabsf(v3.y)), fmaxf(fabsf(v3.z), fabsf(v3.w))));
  }
#pragma unroll
  for (int off = 32; off > 0; off >>= 1) m = fmaxf(m, __shfl_xor(m, off));
  __shared__ float wmax[4];
  int lane = threadIdx.x & 63, wid = threadIdx.x >> 6;
  if (lane == 0) wmax[wid] = m;
  __syncthreads();
  if (threadIdx.x == 0) {
    float mm = fmaxf(fmaxf(wmax[0], wmax[1]), fmaxf(wmax[2], wmax[3]));
    atomicMax(&amax13[e], __float_as_uint(mm));  // R7 bug: was amax13 (expert 0) for all e
  }
}

// ---------- per-pair activation quant ----------
__global__ __launch_bounds__(256) void quantx_k(const float* __restrict__ x,
                                                const int* __restrict__ pair_tok,
                                                const int* __restrict__ offs,
                                                const float* __restrict__ s13,
                                                unsigned char* __restrict__ Xq) {
  int p = blockIdx.x;
  int t = pair_tok[p];
  int e = 0;
#pragma unroll
  for (int j = 1; j < E_NUM; j++) { if (p >= offs[j]) e = j; }
  float inv = 1.f / s13[e];
  float4 v = ((const float4*)(x + (size_t)t * H_DIM))[threadIdx.x];
  float a = fminf(448.f, fmaxf(-448.f, v.x * inv));
  float b = fminf(448.f, fmaxf(-448.f, v.y * inv));
  float c = fminf(448.f, fmaxf(-448.f, v.z * inv));
  float dd = fminf(448.f, fmaxf(-448.f, v.w * inv));
  ((unsigned*)(Xq + (size_t)p * H_DIM))[threadIdx.x] = q4(a, b, c, dd);
}

// ---------- GEMM1: BM=256, BN=32g+32u, BK=64, 512 threads ----------
// blockIdx.x < NT1 : gemm tile.  x >= NT1 (y==0 only): embedded amax2 streaming
// (overlaps w2 amax with gemm1 compute; loads w2 into LLC for gemm2).
__global__ __launch_bounds__(512) void gemm1_k(const float* __restrict__ w13,
                                               const float* __restrict__ w2,
                                               const unsigned char* __restrict__ Xq,
                                               unsigned char* __restrict__ H1,
                                               const int* __restrict__ cnt,
                                               const int* __restrict__ offs,
                                               const unsigned* __restrict__ amax13,
                                               unsigned* __restrict__ amax2,
                                               const float* __restrict__ s13,
                                               const float* __restrict__ s2in) {
  const int e = blockIdx.z;

  if (blockIdx.x >= NT1) {  // ---- embedded amax2 path ----
    if (blockIdx.y != 0) return;
    const int bx = blockIdx.x - NT1;
    const float4* src = (const float4*)w2 + (size_t)e * (H_DIM * I_DIM / 4);
    int idx = bx * 512 + threadIdx.x;
    int stride = AMX2_BLKS * 512;
    float m = 0.f;
#pragma unroll
    for (int j = 0; j < 11; j++) {
      float4 v = src[idx + (size_t)j * stride];
      m = fmaxf(m, fmaxf(fmaxf(fabsf(v.x), fabsf(v.y)), fmaxf(fabsf(v.z), fabsf(v.w))));
    }
#pragma unroll
    for (int off = 32; off > 0; off >>= 1) m = fmaxf(m, __shfl_xor(m, off));
    __shared__ float wmax2[8];
    int lane = threadIdx.x & 63, wid = threadIdx.x >> 6;
    if (lane == 0) wmax2[wid] = m;
    __syncthreads();
    if (threadIdx.x == 0) {
      float mm = wmax2[0];
#pragma unroll
      for (int j = 1; j < 8; j++) mm = fmaxf(mm, wmax2[j]);
      atomicMax(&amax2[e], __float_as_uint(mm));
    }
    return;
  }

  const int count = cnt[e];
  const int m0 = blockIdx.y * 256;
  if (m0 >= count) return;
  const int nt = blockIdx.x;
  const int base = offs[e];

  const float amax = __uint_as_float(amax13[e]);
  const float inv_w = 448.f / amax;
  const float gs = s13[e] * (amax / 448.f);
  const float inv_a2 = 1.f / s2in[e];

  __shared__ __align__(16) unsigned char As[256][80];
  __shared__ __align__(16) unsigned char Bs[64][80];  // rows 0..31 gate, 32..63 up

  const int tid = threadIdx.x, lane = tid & 63, wq = tid >> 6;
  const int fr = lane & 15, ks = lane >> 4;

  f32x4 accg[2][2], accu[2][2];
#pragma unroll
  for (int i = 0; i < 2; i++)
#pragma unroll
    for (int j = 0; j < 2; j++) { accg[i][j] = (f32x4)0.f; accu[i][j] = (f32x4)0.f; }

  const int ar0 = tid >> 2, ar1 = (tid + 512) >> 2, aseg = tid & 3;
  int pr0 = base + m0 + ar0; if (pr0 > PAIRS - 1) pr0 = PAIRS - 1;
  int pr1 = base + m0 + ar1; if (pr1 > PAIRS - 1) pr1 = PAIRS - 1;
  const unsigned char* a_src0 = Xq + (size_t)pr0 * H_DIM + aseg * 16;
  const unsigned char* a_src1 = Xq + (size_t)pr1 * H_DIM + aseg * 16;

  const int brow = tid >> 3, bseg = tid & 7;
  const size_t brg = (size_t)nt * 32 + (brow & 31) + (size_t)(brow >> 5) * I_DIM;
  const float* b_src = w13 + ((size_t)e * 2 * I_DIM + brg) * H_DIM + bseg * 8;

  u32x4 ra0 = *(const u32x4*)a_src0;
  u32x4 ra1 = *(const u32x4*)a_src1;
  float4 fb0 = ((const float4*)b_src)[0], fb1 = ((const float4*)b_src)[1];
  unsigned qb0 = q4v(fb0, inv_w), qb1 = q4v(fb1, inv_w);

  for (int t = 0; t < H_DIM / 64; ++t) {
    __syncthreads();
    *(u32x4*)&As[ar0][aseg * 16] = ra0;
    *(u32x4*)&As[ar1][aseg * 16] = ra1;
    ((unsigned*)&Bs[brow][bseg * 8])[0] = qb0;
    ((unsigned*)&Bs[brow][bseg * 8])[1] = qb1;
    __syncthreads();
    if (t + 1 < H_DIM / 64) {
      int k0 = (t + 1) * 64;
      ra0 = *(const u32x4*)(a_src0 + k0);
      ra1 = *(const u32x4*)(a_src1 + k0);
      fb0 = ((const float4*)(b_src + k0))[0];
      fb1 = ((const float4*)(b_src + k0))[1];
    }
#pragma unroll
    for (int kk = 0; kk < 2; kk++) {
      i64 a0 = *(const i64*)&As[wq * 32 + fr][kk * 32 + ks * 8];
      i64 a1 = *(const i64*)&As[wq * 32 + 16 + fr][kk * 32 + ks * 8];
#pragma unroll
      for (int ni = 0; ni < 2; ni++) {
        i64 bg = *(const i64*)&Bs[ni * 16 + fr][kk * 32 + ks * 8];
        i64 bu = *(const i64*)&Bs[32 + ni * 16 + fr][kk * 32 + ks * 8];
        accg[0][ni] = __builtin_amdgcn_mfma_f32_16x16x32_fp8_fp8(a0, bg, accg[0][ni], 0, 0, 0);
        accg[1][ni] = __builtin_amdgcn_mfma_f32_16x16x32_fp8_fp8(a1, bg, accg[1][ni], 0, 0, 0);
        accu[0][ni] = __builtin_amdgcn_mfma_f32_16x16x32_fp8_fp8(a0, bu, accu[0][ni], 0, 0, 0);
        accu[1][ni] = __builtin_amdgcn_mfma_f32_16x16x32_fp8_fp8(a1, bu, accu[1][ni], 0, 0, 0);
      }
    }
    qb0 = q4v(fb0, inv_w);  // vmcnt wait lands here, after MFMA block
    qb1 = q4v(fb1, inv_w);
  }

  const int rg = lane >> 4;
#pragma unroll
  for (int mi = 0; mi < 2; mi++) {
#pragma unroll
    for (int rr = 0; rr < 4; rr++) {
      int lrow = wq * 32 + mi * 16 + rg * 4 + rr;
      if (m0 + lrow < count) {
        size_t p = (size_t)(base + m0 + lrow);
#pragma unroll
        for (int ni = 0; ni < 2; ni++) {
          int col = nt * 32 + ni * 16 + fr;
          float g = accg[mi][ni][rr] * gs;
          float u = accu[mi][ni][rr] * gs;
          float act = g / (1.f + expf(-g)) * u * inv_a2;
          act = fminf(448.f, fmaxf(-448.f, act));
          H1[p * I_DIM + col] = q1(act);
        }
      }
    }
  }
}

// ---------- GEMM2: split-K, BM=128, BN=64, BK=64, 512 threads ----------
__global__ __launch_bounds__(512) void gemm2_k(const float* __restrict__ w2,
                                               const unsigned char* __restrict__ H1,
                                               float* __restrict__ Op,
                                               const int* __restrict__ cnt,
                                               const int* __restrict__ offs,
                                               const unsigned* __restrict__ amax2,
                                               const float* __restrict__ s2in,
                                               const float* __restrict__ pair_w) {
  const int e = blockIdx.z;
  const int count = cnt[e];
  const int m0 = blockIdx.y * 128;
  if (m0 >= count) return;
  const int nt = blockIdx.x & 15;
  const int ksp = blockIdx.x >> 4;
  const int n0 = nt * 64;
  const int base = offs[e];

  const float amax = __uint_as_float(amax2[e]);
  const float inv_w = 448.f / amax;
  const float s2 = s2in[e] * (amax / 448.f);

  __shared__ __align__(16) unsigned char As[128][80];
  __shared__ __align__(16) unsigned char Bs[64][80];

  const int tid = threadIdx.x, lane = tid & 63, wq = tid >> 6;
  const int fr = lane & 15, ks = lane >> 4;

  f32x4 acc[4];
#pragma unroll
  for (int i = 0; i < 4; i++) acc[i] = (f32x4)0.f;

  const int arow = tid >> 2, aseg = tid & 3;
  int pr = base + m0 + arow; if (pr > PAIRS - 1) pr = PAIRS - 1;
  const unsigned char* a_src = H1 + (size_t)pr * I_DIM + aseg * 16;

  const int brow = tid >> 3, bseg = tid & 7;
  const float* b_src = w2 + ((size_t)e * H_DIM + n0 + brow) * I_DIM + bseg * 8;

  const int KITER = (I_DIM / 64) / KSPLIT;  // 11
  const int kbase = ksp * KITER * 64;

  u32x4 ra = *(const u32x4*)(a_src + kbase);
  float4 fb0 = ((const float4*)(b_src + kbase))[0];
  float4 fb1 = ((const float4*)(b_src + kbase))[1];
  unsigned qb0 = q4v(fb0, inv_w), qb1 = q4v(fb1, inv_w);

  for (int t = 0; t < KITER; ++t) {
    __syncthreads();
    *(u32x4*)&As[arow][aseg * 16] = ra;
    ((unsigned*)&Bs[brow][bseg * 8])[0] = qb0;
    ((unsigned*)&Bs[brow][bseg * 8])[1] = qb1;
    __syncthreads();
    if (t + 1 < KITER) {
      int k0 = kbase + (t + 1) * 64;
      ra = *(const u32x4*)(a_src + k0);
      fb0 = ((const float4*)(b_src + k0))[0];
      fb1 = ((const float4*)(b_src + k0))[1];
    }
#pragma unroll
    for (int kk = 0; kk < 2; kk++) {
      i64 a0 = *(const i64*)&As[wq * 16 + fr][kk * 32 + ks * 8];
#pragma unroll
      for (int ni = 0; ni < 4; ni++) {
        i64 b = *(const i64*)&Bs[ni * 16 + fr][kk * 32 + ks * 8];
        acc[ni] = __builtin_amdgcn_mfma_f32_16x16x32_fp8_fp8(a0, b, acc[ni], 0, 0, 0);
      }
    }
    qb0 = q4v(fb0, inv_w);  // vmcnt wait after MFMA block
    qb1 = q4v(fb1, inv_w);
  }

  const int rg = lane >> 4;
#pragma unroll
  for (int rr = 0; rr < 4; rr++) {
    int lrow = wq * 16 + rg * 4 + rr;
    if (m0 + lrow < count) {
      size_t p = (size_t)(base + m0 + lrow);
      float pw = pair_w[p];
#pragma unroll
      for (int ni = 0; ni < 4; ni++) {
        int col = n0 + ni * 16 + fr;
        Op[((size_t)ksp * PAIRS + p) * H_DIM + col] = acc[ni][rr] * s2 * pw;
      }
    }
  }
}

// ---------- combine: out[t,:] = sum over 2 pairs x KSPLIT partials (fixed order) ----------
__global__ __launch_bounds__(256) void combine_k(const float* __restrict__ Op,
                                                 const int* __restrict__ pairidx,
                                                 float* __restrict__ out) {
  int t = blockIdx.x;
  int p0 = pairidx[2 * t], p1 = pairidx[2 * t + 1];
  f32x4 acc = (f32x4)0.f;
#pragma unroll
  for (int s = 0; s < KSPLIT; s++) {
    f32x4 a = ((const f32x4*)(Op + ((size_t)s * PAIRS + p0) * H_DIM))[threadIdx.x];
    f32x4 b = ((const f32x4*)(Op + ((size_t)s * PAIRS + p1) * H_DIM))[threadIdx.x];
    acc += a + b;
  }
  ((f32x4*)(out + (size_t)t * H_DIM))[threadIdx.x] = acc;
}

extern "C" void kernel_launch(void* const* d_in, const int* in_sizes, int n_in,
                              void* d_out, int out_size, void* d_ws, size_t ws_size,
                              hipStream_t stream) {
  (void)in_sizes; (void)n_in; (void)out_size; (void)ws_size;
  const float* x      = (const float*)d_in[0];
  const float* logits = (const float*)d_in[1];
  const float* w13    = (const float*)d_in[2];
  const float* w2     = (const float*)d_in[3];
  const float* s13    = (const float*)d_in[4];
  const float* s2in   = (const float*)d_in[5];
  float* out = (float*)d_out;

  char* ws = (char*)d_ws;
  unsigned* amax13 = (unsigned*)(ws + 0);
  unsigned* amax2  = (unsigned*)(ws + 64);
  int* cnt     = (int*)(ws + 128);
  int* offs    = (int*)(ws + 192);
  int* pair_tok = (int*)(ws + 17408);
  float* pair_w = (float*)(ws + 25600);
  int* pairidx  = (int*)(ws + 33792);
  unsigned char* Xq = (unsigned char*)(ws + (size_t)(1 << 20));        // 2 MB
  unsigned char* H1 = (unsigned char*)(ws + (size_t)4 * (1 << 20));    // 5.77 MB
  float* Op         = (float*)(ws + (size_t)10 * (1 << 20));           // KSPLIT*8 MB

  route_k<<<1, 1024, 0, stream>>>(logits, amax13, amax2, cnt, offs,
                                  pair_tok, pair_w, pairidx);

  // w13 amax right before gemm1 -> w13 LLC-warm for the GEMM re-read
  amax13_k<<<dim3(128, E_NUM), 256, 0, stream>>>(w13, amax13);

  quantx_k<<<PAIRS, 256, 0, stream>>>(x, pair_tok, offs, s13, Xq);

  // gemm1 + embedded amax2 streaming (overlap; warms LLC with w2 for gemm2)
  gemm1_k<<<dim3(NT1 + AMX2_BLKS, 4, E_NUM), 512, 0, stream>>>(
      w13, w2, Xq, H1, cnt, offs, amax13, amax2, s13, s2in);

  gemm2_k<<<dim3(16 * KSPLIT, 8, E_NUM), 512, 0, stream>>>(
      w2, H1, Op, cnt, offs, amax2, s2in, pair_w);

  combine_k<<<T_TOK, 256, 0, stream>>>(Op, pairidx, out);
}